// Round 4
// baseline (4724.105 us; speedup 1.0000x reference)
//
#include <hip/hip_runtime.h>
#include <hip/hip_bf16.h>
#include <math.h>

#define NNODES 50000
#define NEDGES 800000
#define HD     256   // HEADS*DHEAD

typedef __hip_bfloat16 bf16;
typedef unsigned short u16;
typedef unsigned int   u32;

__device__ __forceinline__ float b2f(bf16 v) { return __bfloat162float(v); }
__device__ __forceinline__ float ldf(const float* p) { return *p; }
__device__ __forceinline__ float ldf(const bf16* p)  { return __bfloat162float(*p); }
__device__ __forceinline__ u16 f2bb(float v) { __hip_bfloat16 h = __float2bfloat16(v); return *(u16*)&h; }

// ---------------- CSR build ----------------
__global__ void hist_kernel(const int* __restrict__ dst, int* __restrict__ deg, int E) {
    int e = blockIdx.x * 256 + threadIdx.x;
    if (e < E) atomicAdd(&deg[dst[e]], 1);
}

__global__ void scan_kernel(const int* __restrict__ deg, int* __restrict__ rowptr,
                            int* __restrict__ cursor, int n) {
    __shared__ int sh[1024];
    int running = 0;
    for (int base = 0; base < n; base += 1024) {
        int i = base + threadIdx.x;
        int d = (i < n) ? deg[i] : 0;
        sh[threadIdx.x] = d;
        __syncthreads();
        for (int off = 1; off < 1024; off <<= 1) {
            int t = (threadIdx.x >= (unsigned)off) ? sh[threadIdx.x - off] : 0;
            __syncthreads();
            sh[threadIdx.x] += t;
            __syncthreads();
        }
        int incl = sh[threadIdx.x];
        int tot  = sh[1023];
        __syncthreads();
        if (i < n) {
            int ex = running + incl - d;
            rowptr[i] = ex;
            cursor[i] = ex;
        }
        running += tot;
    }
    if (threadIdx.x == 0) rowptr[n] = running;
}

__global__ void scatter_kernel(const int* __restrict__ src, const int* __restrict__ dst,
                               int* __restrict__ cursor, int2* __restrict__ csr2, int E) {
    int e = blockIdx.x * 256 + threadIdx.x;
    if (e < E) {
        int p = atomicAdd(&cursor[dst[e]], 1);
        csr2[p] = make_int2(src[e], e);
    }
}

// ---------------- weight precompute ----------------
__global__ void cast_f32_bf16(const float* __restrict__ in, bf16* __restrict__ out, int n) {
    int i = blockIdx.x * 256 + threadIdx.x;
    if (i < n) out[i] = __float2bfloat16(in[i]);
}

// WqWe[c][h*16+j] = sum_d Wq[c, h*64+d] * We[j, h*64+d]; row c==FIN holds the bq-derived bias.
__global__ void wqwe_kernel(const float* __restrict__ Wq, const float* __restrict__ bq,
                            const float* __restrict__ We, float* __restrict__ out, int FIN) {
    int c = blockIdx.x;              // 0..FIN inclusive
    int t = threadIdx.x;             // 64: h = t>>4, j = t&15
    int h = t >> 4, j = t & 15;
    const float* qrow = (c == FIN) ? bq : (Wq + (size_t)c * HD);
    float s = 0.f;
    #pragma unroll 8
    for (int d = 0; d < 64; d++) s += qrow[h * 64 + d] * We[j * HD + h * 64 + d];
    out[c * 64 + t] = s;
}

// ------- fused k+v GEMM: writes packed u32 (k low u16, v high u16) per channel -------
template<typename TA>
__global__ void __launch_bounds__(256) gemm_kv(
    const TA* __restrict__ A, int K,
    const float* __restrict__ Wk, const float* __restrict__ bk,
    const float* __restrict__ Wv, const float* __restrict__ bv,
    int M, u16* __restrict__ kvp)
{
    __shared__ float As[32][68];
    __shared__ float Bs[32][68];
    int m0 = blockIdx.x * 64;
    int cb = blockIdx.y * 64;                // 0..511
    int sel = (cb >= 256) ? 1 : 0;
    const float* W    = sel ? Wv : Wk;
    const float* bias = sel ? bv : bk;
    int wc = cb & 255;
    int tid = threadIdx.x;
    int tx = tid & 15, ty = tid >> 4;
    float acc[4][4] = {};
    for (int k0 = 0; k0 < K; k0 += 32) {
        #pragma unroll
        for (int r = 0; r < 8; r++) {
            int idx = tid + r * 256;          // 64 x 32
            int m = idx >> 5, kk = idx & 31;
            float va = 0.f;
            if (m0 + m < M) va = ldf(&A[(size_t)(m0 + m) * K + k0 + kk]);
            As[kk][m] = va;
        }
        #pragma unroll
        for (int r = 0; r < 8; r++) {
            int idx = tid + r * 256;          // 32 x 64
            int kk = idx >> 6, nn = idx & 63;
            Bs[kk][nn] = W[(size_t)(k0 + kk) * HD + wc + nn];
        }
        __syncthreads();
        #pragma unroll
        for (int kk = 0; kk < 32; kk++) {
            float a[4], b[4];
            #pragma unroll
            for (int i = 0; i < 4; i++) a[i] = As[kk][ty * 4 + i];
            #pragma unroll
            for (int j = 0; j < 4; j++) b[j] = Bs[kk][tx * 4 + j];
            #pragma unroll
            for (int i = 0; i < 4; i++)
                #pragma unroll
                for (int j = 0; j < 4; j++) acc[i][j] += a[i] * b[j];
        }
        __syncthreads();
    }
    #pragma unroll
    for (int i = 0; i < 4; i++) {
        int m = m0 + ty * 4 + i;
        if (m >= M) continue;
        #pragma unroll
        for (int j = 0; j < 4; j++) {
            int c = wc + tx * 4 + j;
            kvp[((size_t)m * HD + c) * 2 + sel] = f2bb(acc[i][j] + bias[c]);
        }
    }
}

// ---------------- fused per-node pass ----------------
// 1024 threads = 16 waves: wave w -> head h = w&3, edge-chunk = w>>2.
// Partial softmax sums combine additively in LDS (no max-subtraction needed).
template<int FIN, typename TH>
__global__ void __launch_bounds__(1024, 8) node_pass(
    const int* __restrict__ rowptr, const int2* __restrict__ csr2,
    const float* __restrict__ eattr, const TH* __restrict__ hin,
    const bf16* __restrict__ WqB, const float* __restrict__ bq,
    const float* __restrict__ WqWe,
    const bf16* __restrict__ WsB, const float* __restrict__ bs,
    const u32* __restrict__ kvp, const bf16* __restrict__ WeB,
    const float* __restrict__ lng, const float* __restrict__ lnb,
    bf16* __restrict__ outB, float* __restrict__ outF)
{
    int n = blockIdx.x;
    int w = threadIdx.x >> 6, lane = threadIdx.x & 63;
    int h = w & 3, chunk = w >> 2;

    __shared__ float sh_h[FIN];
    __shared__ float sh_q[4][64];
    __shared__ float sh_qwe[4][16];
    __shared__ float sv[16][64];
    __shared__ float se[16][16];
    __shared__ float ss[16];

    if (threadIdx.x < FIN) sh_h[threadIdx.x] = ldf(&hin[(size_t)n * FIN + threadIdx.x]);
    __syncthreads();

    if (w < 4) {   // wave w computes head w's q and qWe once per block
        float qh = bq[(w << 6) + lane];
        #pragma unroll 8
        for (int c = 0; c < FIN; c++) qh += sh_h[c] * b2f(WqB[(size_t)c * HD + (w << 6) + lane]);
        sh_q[w][lane] = qh;
        if (lane < 16) {
            float s = WqWe[FIN * 64 + w * 16 + lane];    // bias row
            #pragma unroll 8
            for (int c = 0; c < FIN; c++) s += sh_h[c] * WqWe[c * 64 + w * 16 + lane];
            sh_qwe[w][lane] = s;
        }
    }
    __syncthreads();

    float qh    = sh_q[h][lane];
    float qwe_l = (lane < 16) ? sh_qwe[h][lane] : 0.f;

    int e0 = rowptr[n], e1 = rowptr[n + 1];
    int len  = (e1 - e0 + 3) >> 2;
    int ibeg = e0 + chunk * len;
    int iend = ibeg + len; if (iend > e1) iend = e1;

    float accv = 0.f, acce = 0.f, ssum = 0.f;
    for (int i = ibeg; i < iend; i++) {
        int2 sp = csr2[i];                               // uniform 8B load
        u32 u = kvp[(size_t)sp.x * HD + (h << 6) + lane]; // packed k|v gather
        float kf = __uint_as_float(u << 16);
        float vf = __uint_as_float(u & 0xFFFF0000u);
        float eav = (lane < 16) ? eattr[(size_t)sp.y * 16 + lane] : 0.f;
        float t = qh * kf + eav * qwe_l;
        #pragma unroll
        for (int off = 1; off < 64; off <<= 1) t += __shfl_xor(t, off);
        float a = __expf(t * 0.125f);                    // SCALE = 1/sqrt(64)
        ssum += a;
        accv += a * vf;
        acce += a * eav;
    }
    sv[w][lane] = accv;
    if (lane < 16) se[w][lane] = acce;
    if (lane == 0) ss[w] = ssum;
    __syncthreads();

    if (w < 4) {   // combine 4 chunks for head w, then normalize
        float AV = 0.f, S = 0.f, AE = 0.f;
        #pragma unroll
        for (int c = 0; c < 4; c++) {
            AV += sv[c * 4 + w][lane];
            S  += ss[c * 4 + w];
            if (lane < 16) AE += se[c * 4 + w][lane];
        }
        float inv = (S > 0.f) ? 1.f / S : 0.f;
        sv[w][lane] = AV * inv;
        if (lane < 16) se[w][lane] = AE * inv;
    }
    __syncthreads();

    if (w == 0) {
        int d = lane;
        float skipd = bs[d];
        #pragma unroll 8
        for (int c = 0; c < FIN; c++) skipd += sh_h[c] * b2f(WsB[(size_t)c * 64 + d]);
        float val = 0.f;
        #pragma unroll
        for (int hh = 0; hh < 4; hh++) {
            float xv = sv[hh][d];
            #pragma unroll
            for (int j = 0; j < 16; j++) xv += se[hh][j] * b2f(WeB[j * HD + hh * 64 + d]);
            val += xv;
        }
        val = val * 0.25f + skipd;
        float m = val;
        #pragma unroll
        for (int off = 1; off < 64; off <<= 1) m += __shfl_xor(m, off);
        m *= (1.f / 64.f);
        float diff = val - m;
        float vr = diff * diff;
        #pragma unroll
        for (int off = 1; off < 64; off <<= 1) vr += __shfl_xor(vr, off);
        vr *= (1.f / 64.f);
        float y = diff * rsqrtf(vr + 1e-5f) * lng[d] + lnb[d];
        float ge = 0.5f * y * (1.f + erff(y * 0.70710678118654752f));
        if (outF) outF[(size_t)n * 64 + d] = ge;
        else      outB[(size_t)n * 64 + d] = __float2bfloat16(ge);
    }
}

extern "C" void kernel_launch(void* const* d_in, const int* in_sizes, int n_in,
                              void* d_out, int out_size, void* d_ws, size_t ws_size,
                              hipStream_t stream)
{
    const float* x     = (const float*)d_in[0];
    const int*   eidx  = (const int*)d_in[1];
    const float* eattr = (const float*)d_in[2];
    struct P { const float *Wq,*bq,*Wk,*bk,*Wv,*bv,*We,*Ws,*bs; };
    P p[3];
    for (int l = 0; l < 3; l++) {
        int base = 3 + l * 9;
        p[l].Wq = (const float*)d_in[base + 0]; p[l].bq = (const float*)d_in[base + 1];
        p[l].Wk = (const float*)d_in[base + 2]; p[l].bk = (const float*)d_in[base + 3];
        p[l].Wv = (const float*)d_in[base + 4]; p[l].bv = (const float*)d_in[base + 5];
        p[l].We = (const float*)d_in[base + 6];
        p[l].Ws = (const float*)d_in[base + 7]; p[l].bs = (const float*)d_in[base + 8];
    }
    const float* lng = (const float*)d_in[30];
    const float* lnb = (const float*)d_in[31];

    // Workspace: ~61.9 MiB
    char* ws = (char*)d_ws;
    size_t off = 0;
    auto alloc = [&](size_t bytes) { void* pp = ws + off; off += (bytes + 255) & ~(size_t)255; return pp; };
    int*  rowptr = (int*) alloc((NNODES + 1) * 4);
    int*  cursor = (int*) alloc(NNODES * 4);
    int*  deg    = (int*) alloc(NNODES * 4);
    int2* csr2   = (int2*)alloc((size_t)NEDGES * 8);
    bf16* hbuf   = (bf16*)alloc((size_t)NNODES * 64 * 2);
    u16*  kvp    = (u16*) alloc((size_t)NNODES * HD * 4);   // packed u32 per channel
    bf16* wqb[3]; bf16* wsb[3]; bf16* web[3]; float* wqwe[3];
    int fins[3] = {128, 64, 64};
    for (int l = 0; l < 3; l++) {
        wqb[l]  = (bf16*) alloc((size_t)fins[l] * HD * 2);
        wsb[l]  = (bf16*) alloc((size_t)fins[l] * 64 * 2);
        web[l]  = (bf16*) alloc((size_t)16 * HD * 2);
        wqwe[l] = (float*)alloc((size_t)(fins[l] + 1) * 64 * 4);
    }

    const int* srcArr = eidx;           // edge_index[0]
    const int* dstArr = eidx + NEDGES;  // edge_index[1]

    // CSR build
    hipMemsetAsync(deg, 0, NNODES * 4, stream);
    hist_kernel<<<(NEDGES + 255) / 256, 256, 0, stream>>>(dstArr, deg, NEDGES);
    scan_kernel<<<1, 1024, 0, stream>>>(deg, rowptr, cursor, NNODES);
    scatter_kernel<<<(NEDGES + 255) / 256, 256, 0, stream>>>(srcArr, dstArr, cursor, csr2, NEDGES);

    // Weight precompute (cheap, every launch)
    for (int l = 0; l < 3; l++) {
        int fin = fins[l];
        cast_f32_bf16<<<(fin * HD + 255) / 256, 256, 0, stream>>>(p[l].Wq, wqb[l], fin * HD);
        cast_f32_bf16<<<(fin * 64 + 255) / 256, 256, 0, stream>>>(p[l].Ws, wsb[l], fin * 64);
        cast_f32_bf16<<<(16 * HD + 255) / 256, 256, 0, stream>>>(p[l].We, web[l], 16 * HD);
        wqwe_kernel<<<fin + 1, 64, 0, stream>>>(p[l].Wq, p[l].bq, p[l].We, wqwe[l], fin);
    }

    dim3 gkv((NNODES + 63) / 64, 8);
    // Layer 1 (FIN=128, fp32 input)
    gemm_kv<float><<<gkv, 256, 0, stream>>>(x, 128, p[0].Wk, p[0].bk, p[0].Wv, p[0].bv, NNODES, kvp);
    node_pass<128, float><<<NNODES, 1024, 0, stream>>>(rowptr, csr2, eattr, x,
        wqb[0], p[0].bq, wqwe[0], wsb[0], p[0].bs, (const u32*)kvp, web[0], lng, lnb, hbuf, nullptr);
    // Layer 2 (FIN=64, bf16)
    gemm_kv<bf16><<<gkv, 256, 0, stream>>>(hbuf, 64, p[1].Wk, p[1].bk, p[1].Wv, p[1].bv, NNODES, kvp);
    node_pass<64, bf16><<<NNODES, 1024, 0, stream>>>(rowptr, csr2, eattr, hbuf,
        wqb[1], p[1].bq, wqwe[1], wsb[1], p[1].bs, (const u32*)kvp, web[1], lng, lnb, hbuf, nullptr);
    // Layer 3 (FIN=64, bf16) -> fp32 d_out
    gemm_kv<bf16><<<gkv, 256, 0, stream>>>(hbuf, 64, p[2].Wk, p[2].bk, p[2].Wv, p[2].bv, NNODES, kvp);
    node_pass<64, bf16><<<NNODES, 1024, 0, stream>>>(rowptr, csr2, eattr, hbuf,
        wqb[2], p[2].bq, wqwe[2], wsb[2], p[2].bs, (const u32*)kvp, web[2], lng, lnb, nullptr, (float*)d_out);
}

// Round 5
// 3178.285 us; speedup vs baseline: 1.4864x; 1.4864x over previous
//
#include <hip/hip_runtime.h>
#include <hip/hip_bf16.h>
#include <math.h>

#define NNODES 50000
#define NEDGES 800000
#define HD     256   // HEADS*DHEAD

typedef __hip_bfloat16 bf16;
typedef unsigned short u16;
typedef unsigned int   u32;

__device__ __forceinline__ float b2f(bf16 v) { return __bfloat162float(v); }
__device__ __forceinline__ float ldf(const float* p) { return *p; }
__device__ __forceinline__ float ldf(const bf16* p)  { return __bfloat162float(*p); }
__device__ __forceinline__ float lo16f(u32 u) { return __uint_as_float(u << 16); }
__device__ __forceinline__ float hi16f(u32 u) { return __uint_as_float(u & 0xFFFF0000u); }

// ---------------- CSR build ----------------
__global__ void hist_kernel(const int* __restrict__ dst, int* __restrict__ deg, int E) {
    int e = blockIdx.x * 256 + threadIdx.x;
    if (e < E) atomicAdd(&deg[dst[e]], 1);
}

__global__ void scan_kernel(const int* __restrict__ deg, int* __restrict__ rowptr,
                            int* __restrict__ cursor, int n) {
    __shared__ int sh[1024];
    int running = 0;
    for (int base = 0; base < n; base += 1024) {
        int i = base + threadIdx.x;
        int d = (i < n) ? deg[i] : 0;
        sh[threadIdx.x] = d;
        __syncthreads();
        for (int off = 1; off < 1024; off <<= 1) {
            int t = (threadIdx.x >= (unsigned)off) ? sh[threadIdx.x - off] : 0;
            __syncthreads();
            sh[threadIdx.x] += t;
            __syncthreads();
        }
        int incl = sh[threadIdx.x];
        int tot  = sh[1023];
        __syncthreads();
        if (i < n) {
            int ex = running + incl - d;
            rowptr[i] = ex;
            cursor[i] = ex;
        }
        running += tot;
    }
    if (threadIdx.x == 0) rowptr[n] = running;
}

__global__ void scatter_kernel(const int* __restrict__ src, const int* __restrict__ dst,
                               int* __restrict__ cursor, int2* __restrict__ csr2, int E) {
    int e = blockIdx.x * 256 + threadIdx.x;
    if (e < E) {
        int p = atomicAdd(&cursor[dst[e]], 1);
        csr2[p] = make_int2(src[e], e);
    }
}

// ---------------- weight precompute ----------------
__global__ void cast_f32_bf16(const float* __restrict__ in, bf16* __restrict__ out, int n) {
    int i = blockIdx.x * 256 + threadIdx.x;
    if (i < n) out[i] = __float2bfloat16(in[i]);
}

// WqWe[c][h*16+j] = sum_d Wq[c, h*64+d] * We[j, h*64+d]; row c==FIN is the bq-derived bias.
__global__ void wqwe_kernel(const float* __restrict__ Wq, const float* __restrict__ bq,
                            const float* __restrict__ We, float* __restrict__ out, int FIN) {
    int c = blockIdx.x;              // 0..FIN inclusive
    int t = threadIdx.x;             // h = t>>4, j = t&15
    int h = t >> 4, j = t & 15;
    const float* qrow = (c == FIN) ? bq : (Wq + (size_t)c * HD);
    float s = 0.f;
    #pragma unroll 8
    for (int d = 0; d < 64; d++) s += qrow[h * 64 + d] * We[j * HD + h * 64 + d];
    out[c * 64 + t] = s;
}

// ------- fused k+v GEMM -> separate bf16 kb / vb [N][256] -------
template<typename TA>
__global__ void __launch_bounds__(256) gemm_kv(
    const TA* __restrict__ A, int K,
    const float* __restrict__ Wk, const float* __restrict__ bk,
    const float* __restrict__ Wv, const float* __restrict__ bv,
    int M, bf16* __restrict__ kb, bf16* __restrict__ vb)
{
    __shared__ float As[32][68];
    __shared__ float Bs[32][68];
    int m0 = blockIdx.x * 64;
    int sel = (blockIdx.y >= 4) ? 1 : 0;
    int wc  = (blockIdx.y & 3) * 64;
    const float* W    = sel ? Wv : Wk;
    const float* bias = sel ? bv : bk;
    bf16* out = sel ? vb : kb;
    int tid = threadIdx.x;
    int tx = tid & 15, ty = tid >> 4;
    float acc[4][4] = {};
    for (int k0 = 0; k0 < K; k0 += 32) {
        #pragma unroll
        for (int r = 0; r < 8; r++) {
            int idx = tid + r * 256;          // 64 x 32
            int m = idx >> 5, kk = idx & 31;
            float va = 0.f;
            if (m0 + m < M) va = ldf(&A[(size_t)(m0 + m) * K + k0 + kk]);
            As[kk][m] = va;
        }
        #pragma unroll
        for (int r = 0; r < 8; r++) {
            int idx = tid + r * 256;          // 32 x 64
            int kk = idx >> 6, nn = idx & 63;
            Bs[kk][nn] = W[(size_t)(k0 + kk) * HD + wc + nn];
        }
        __syncthreads();
        #pragma unroll
        for (int kk = 0; kk < 32; kk++) {
            float a[4], b[4];
            #pragma unroll
            for (int i = 0; i < 4; i++) a[i] = As[kk][ty * 4 + i];
            #pragma unroll
            for (int j = 0; j < 4; j++) b[j] = Bs[kk][tx * 4 + j];
            #pragma unroll
            for (int i = 0; i < 4; i++)
                #pragma unroll
                for (int j = 0; j < 4; j++) acc[i][j] += a[i] * b[j];
        }
        __syncthreads();
    }
    #pragma unroll
    for (int i = 0; i < 4; i++) {
        int m = m0 + ty * 4 + i;
        if (m >= M) continue;
        #pragma unroll
        for (int j = 0; j < 4; j++) {
            int c = wc + tx * 4 + j;
            out[(size_t)m * HD + c] = __float2bfloat16(acc[i][j] + bias[c]);
        }
    }
}

// ---------------- fused per-node pass (256 threads = 4 waves) ----------------
// Stage 1: thread t -> (edge t>>2, head t&3) streams the 128B k-row, no cross-lane ops.
// Stage 2: wave w = head w, lane = channel; LDS-broadcast alpha, coalesced v-row gather.
template<int FIN, typename TH>
__global__ void __launch_bounds__(256) node_pass(
    const int* __restrict__ rowptr, const int2* __restrict__ csr2,
    const float* __restrict__ eattr, const TH* __restrict__ hin,
    const bf16* __restrict__ WqB, const float* __restrict__ bq,
    const float* __restrict__ WqWe,
    const bf16* __restrict__ WsB, const float* __restrict__ bs,
    const bf16* __restrict__ kb, const bf16* __restrict__ vb,
    const bf16* __restrict__ WeB,
    const float* __restrict__ lng, const float* __restrict__ lnb,
    bf16* __restrict__ outB, float* __restrict__ outF)
{
    int n = blockIdx.x;
    int tid = threadIdx.x;
    int w = tid >> 6, lane = tid & 63;

    __shared__ float sh_h[FIN];
    __shared__ float sh_q[4][64];
    __shared__ float sh_qwe[4][16];
    __shared__ float sh_alpha[256];      // [e*4 + h]
    __shared__ float sh_ea[64][16];
    __shared__ int   sh_src[64];
    __shared__ int   sh_eid[64];
    __shared__ float sv[4][64];
    __shared__ float se[4][16];

    if (tid < FIN) sh_h[tid] = ldf(&hin[(size_t)n * FIN + tid]);
    __syncthreads();

    // wave w computes head w's q and qWe
    {
        float qh = bq[(w << 6) + lane];
        #pragma unroll 8
        for (int c = 0; c < FIN; c++) qh += sh_h[c] * b2f(WqB[(size_t)c * HD + (w << 6) + lane]);
        sh_q[w][lane] = qh;
        if (lane < 16) {
            float s = WqWe[FIN * 64 + w * 16 + lane];    // bias row
            #pragma unroll 8
            for (int c = 0; c < FIN; c++) s += sh_h[c] * WqWe[c * 64 + w * 16 + lane];
            sh_qwe[w][lane] = s;
        }
    }
    __syncthreads();

    int e0 = rowptr[n], e1 = rowptr[n + 1];
    float accv = 0.f, acce = 0.f, ssum = 0.f;

    for (int base = e0; base < e1; base += 64) {
        int cnt = e1 - base; if (cnt > 64) cnt = 64;
        if (tid < cnt) {
            int2 sp = csr2[base + tid];
            sh_src[tid] = sp.x;
            sh_eid[tid] = sp.y;
        }
        __syncthreads();

        // ---- stage 1: logits/alphas, thread-per-(edge,head) ----
        {
            int e = tid >> 2, hh = tid & 3;
            float a = 0.f;
            if (e < cnt) {
                const uint2* k2 = (const uint2*)((const u16*)kb + (size_t)sh_src[e] * HD + (hh << 6));
                float t = 0.f;
                #pragma unroll
                for (int i = 0; i < 16; i++) {
                    uint2 u = k2[i];
                    t += sh_q[hh][i * 4 + 0] * lo16f(u.x)
                       + sh_q[hh][i * 4 + 1] * hi16f(u.x)
                       + sh_q[hh][i * 4 + 2] * lo16f(u.y)
                       + sh_q[hh][i * 4 + 3] * hi16f(u.y);
                }
                const float4* ep = (const float4*)(eattr + (size_t)sh_eid[e] * 16);
                #pragma unroll
                for (int j = 0; j < 4; j++) {
                    float4 v4 = ep[j];
                    t += sh_qwe[hh][j * 4 + 0] * v4.x + sh_qwe[hh][j * 4 + 1] * v4.y
                       + sh_qwe[hh][j * 4 + 2] * v4.z + sh_qwe[hh][j * 4 + 3] * v4.w;
                    if (hh == 0) *(float4*)&sh_ea[e][j * 4] = v4;
                }
                a = __expf(t * 0.125f);      // SCALE = 1/sqrt(64)
            }
            sh_alpha[tid] = a;               // tid == e*4 + hh
        }
        __syncthreads();

        // ---- stage 2: aggregation, wave-per-head ----
        const u16* vbase = (const u16*)vb;
        #pragma unroll 4
        for (int e2 = 0; e2 < cnt; e2++) {
            float a2 = sh_alpha[e2 * 4 + w];                 // LDS broadcast
            u16 vraw = vbase[(size_t)sh_src[e2] * HD + (w << 6) + lane];
            ssum += a2;
            accv += a2 * __uint_as_float((u32)vraw << 16);
            if (lane < 16) acce += a2 * sh_ea[e2][lane];
        }
        __syncthreads();   // protect sh_src/sh_alpha/sh_ea before next chunk
    }

    float inv = (ssum > 0.f) ? 1.f / ssum : 0.f;
    sv[w][lane] = accv * inv;
    if (lane < 16) se[w][lane] = acce * inv;
    __syncthreads();

    if (w == 0) {
        int d = lane;
        float skipd = bs[d];
        #pragma unroll 8
        for (int c = 0; c < FIN; c++) skipd += sh_h[c] * b2f(WsB[(size_t)c * 64 + d]);
        float val = 0.f;
        #pragma unroll
        for (int hh = 0; hh < 4; hh++) {
            float xv = sv[hh][d];
            #pragma unroll
            for (int j = 0; j < 16; j++) xv += se[hh][j] * b2f(WeB[j * HD + hh * 64 + d]);
            val += xv;
        }
        val = val * 0.25f + skipd;
        float m = val;
        #pragma unroll
        for (int off = 1; off < 64; off <<= 1) m += __shfl_xor(m, off);
        m *= (1.f / 64.f);
        float diff = val - m;
        float vr = diff * diff;
        #pragma unroll
        for (int off = 1; off < 64; off <<= 1) vr += __shfl_xor(vr, off);
        vr *= (1.f / 64.f);
        float y = diff * rsqrtf(vr + 1e-5f) * lng[d] + lnb[d];
        float ge = 0.5f * y * (1.f + erff(y * 0.70710678118654752f));
        if (outF) outF[(size_t)n * 64 + d] = ge;
        else      outB[(size_t)n * 64 + d] = __float2bfloat16(ge);
    }
}

extern "C" void kernel_launch(void* const* d_in, const int* in_sizes, int n_in,
                              void* d_out, int out_size, void* d_ws, size_t ws_size,
                              hipStream_t stream)
{
    const float* x     = (const float*)d_in[0];
    const int*   eidx  = (const int*)d_in[1];
    const float* eattr = (const float*)d_in[2];
    struct P { const float *Wq,*bq,*Wk,*bk,*Wv,*bv,*We,*Ws,*bs; };
    P p[3];
    for (int l = 0; l < 3; l++) {
        int base = 3 + l * 9;
        p[l].Wq = (const float*)d_in[base + 0]; p[l].bq = (const float*)d_in[base + 1];
        p[l].Wk = (const float*)d_in[base + 2]; p[l].bk = (const float*)d_in[base + 3];
        p[l].Wv = (const float*)d_in[base + 4]; p[l].bv = (const float*)d_in[base + 5];
        p[l].We = (const float*)d_in[base + 6];
        p[l].Ws = (const float*)d_in[base + 7]; p[l].bs = (const float*)d_in[base + 8];
    }
    const float* lng = (const float*)d_in[30];
    const float* lnb = (const float*)d_in[31];

    // Workspace: ~65 MiB
    char* ws = (char*)d_ws;
    size_t off = 0;
    auto alloc = [&](size_t bytes) { void* pp = ws + off; off += (bytes + 255) & ~(size_t)255; return pp; };
    int*  rowptr = (int*) alloc((NNODES + 1) * 4);
    int*  cursor = (int*) alloc(NNODES * 4);
    int*  deg    = (int*) alloc(NNODES * 4);
    int2* csr2   = (int2*)alloc((size_t)NEDGES * 8);
    bf16* hbuf   = (bf16*)alloc((size_t)NNODES * 64 * 2);
    bf16* kb     = (bf16*)alloc((size_t)NNODES * HD * 2);
    bf16* vb     = (bf16*)alloc((size_t)NNODES * HD * 2);
    bf16* wqb[3]; bf16* wsb[3]; bf16* web[3]; float* wqwe[3];
    int fins[3] = {128, 64, 64};
    for (int l = 0; l < 3; l++) {
        wqb[l]  = (bf16*) alloc((size_t)fins[l] * HD * 2);
        wsb[l]  = (bf16*) alloc((size_t)fins[l] * 64 * 2);
        web[l]  = (bf16*) alloc((size_t)16 * HD * 2);
        wqwe[l] = (float*)alloc((size_t)(fins[l] + 1) * 64 * 4);
    }

    const int* srcArr = eidx;           // edge_index[0]
    const int* dstArr = eidx + NEDGES;  // edge_index[1]

    // CSR build
    hipMemsetAsync(deg, 0, NNODES * 4, stream);
    hist_kernel<<<(NEDGES + 255) / 256, 256, 0, stream>>>(dstArr, deg, NEDGES);
    scan_kernel<<<1, 1024, 0, stream>>>(deg, rowptr, cursor, NNODES);
    scatter_kernel<<<(NEDGES + 255) / 256, 256, 0, stream>>>(srcArr, dstArr, cursor, csr2, NEDGES);

    // Weight precompute
    for (int l = 0; l < 3; l++) {
        int fin = fins[l];
        cast_f32_bf16<<<(fin * HD + 255) / 256, 256, 0, stream>>>(p[l].Wq, wqb[l], fin * HD);
        cast_f32_bf16<<<(fin * 64 + 255) / 256, 256, 0, stream>>>(p[l].Ws, wsb[l], fin * 64);
        cast_f32_bf16<<<(16 * HD + 255) / 256, 256, 0, stream>>>(p[l].We, web[l], 16 * HD);
        wqwe_kernel<<<fin + 1, 64, 0, stream>>>(p[l].Wq, p[l].bq, p[l].We, wqwe[l], fin);
    }

    dim3 gkv((NNODES + 63) / 64, 8);
    // Layer 1 (FIN=128, fp32 input)
    gemm_kv<float><<<gkv, 256, 0, stream>>>(x, 128, p[0].Wk, p[0].bk, p[0].Wv, p[0].bv, NNODES, kb, vb);
    node_pass<128, float><<<NNODES, 256, 0, stream>>>(rowptr, csr2, eattr, x,
        wqb[0], p[0].bq, wqwe[0], wsb[0], p[0].bs, kb, vb, web[0], lng, lnb, hbuf, nullptr);
    // Layer 2 (FIN=64, bf16)
    gemm_kv<bf16><<<gkv, 256, 0, stream>>>(hbuf, 64, p[1].Wk, p[1].bk, p[1].Wv, p[1].bv, NNODES, kb, vb);
    node_pass<64, bf16><<<NNODES, 256, 0, stream>>>(rowptr, csr2, eattr, hbuf,
        wqb[1], p[1].bq, wqwe[1], wsb[1], p[1].bs, kb, vb, web[1], lng, lnb, hbuf, nullptr);
    // Layer 3 (FIN=64, bf16) -> fp32 d_out
    gemm_kv<bf16><<<gkv, 256, 0, stream>>>(hbuf, 64, p[2].Wk, p[2].bk, p[2].Wv, p[2].bv, NNODES, kb, vb);
    node_pass<64, bf16><<<NNODES, 256, 0, stream>>>(rowptr, csr2, eattr, hbuf,
        wqb[2], p[2].bq, wqwe[2], wsb[2], p[2].bs, kb, vb, web[2], lng, lnb, nullptr, (float*)d_out);
}

// Round 6
// 2526.307 us; speedup vs baseline: 1.8700x; 1.2581x over previous
//
#include <hip/hip_runtime.h>
#include <hip/hip_bf16.h>
#include <math.h>

#define NNODES 50000
#define NEDGES 800000
#define HD     256   // HEADS*DHEAD

typedef __hip_bfloat16 bf16;
typedef unsigned short u16;
typedef unsigned int   u32;

__device__ __forceinline__ float b2f(bf16 v) { return __bfloat162float(v); }
__device__ __forceinline__ float ldf(const float* p) { return *p; }
__device__ __forceinline__ float ldf(const bf16* p)  { return __bfloat162float(*p); }
__device__ __forceinline__ float lo16f(u32 u) { return __uint_as_float(u << 16); }
__device__ __forceinline__ float hi16f(u32 u) { return __uint_as_float(u & 0xFFFF0000u); }

// ---------------- CSR build ----------------
__global__ void hist_kernel(const int* __restrict__ dst, int* __restrict__ deg, int E) {
    int e = blockIdx.x * 256 + threadIdx.x;
    if (e < E) atomicAdd(&deg[dst[e]], 1);
}

__global__ void scan_kernel(const int* __restrict__ deg, int* __restrict__ rowptr,
                            int* __restrict__ cursor, int n) {
    __shared__ int sh[1024];
    int running = 0;
    for (int base = 0; base < n; base += 1024) {
        int i = base + threadIdx.x;
        int d = (i < n) ? deg[i] : 0;
        sh[threadIdx.x] = d;
        __syncthreads();
        for (int off = 1; off < 1024; off <<= 1) {
            int t = (threadIdx.x >= (unsigned)off) ? sh[threadIdx.x - off] : 0;
            __syncthreads();
            sh[threadIdx.x] += t;
            __syncthreads();
        }
        int incl = sh[threadIdx.x];
        int tot  = sh[1023];
        __syncthreads();
        if (i < n) {
            int ex = running + incl - d;
            rowptr[i] = ex;
            cursor[i] = ex;
        }
        running += tot;
    }
    if (threadIdx.x == 0) rowptr[n] = running;
}

__global__ void scatter_kernel(const int* __restrict__ src, const int* __restrict__ dst,
                               int* __restrict__ cursor, int2* __restrict__ csr2, int E) {
    int e = blockIdx.x * 256 + threadIdx.x;
    if (e < E) {
        int p = atomicAdd(&cursor[dst[e]], 1);
        csr2[p] = make_int2(src[e], e);
    }
}

// WqWe[c][h*16+j] = sum_d Wq[c, h*64+d] * We[j, h*64+d]; row c==FIN is the bq-derived bias.
__global__ void wqwe_kernel(const float* __restrict__ Wq, const float* __restrict__ bq,
                            const float* __restrict__ We, float* __restrict__ out, int FIN) {
    int c = blockIdx.x;              // 0..FIN inclusive
    int t = threadIdx.x;             // h = t>>4, j = t&15
    int h = t >> 4, j = t & 15;
    const float* qrow = (c == FIN) ? bq : (Wq + (size_t)c * HD);
    float s = 0.f;
    #pragma unroll 8
    for (int d = 0; d < 64; d++) s += qrow[h * 64 + d] * We[j * HD + h * 64 + d];
    out[c * 64 + t] = s;
}

// ------- generic tiled GEMM: out[M x ldo](bf16) = A[M x K] @ W[K x ldw](fp32) + bias, fp32 acc -------
template<typename TA>
__global__ void __launch_bounds__(256) gemm_bias(
    const TA* __restrict__ A, int K,
    const float* __restrict__ W, int ldw,
    const float* __restrict__ bias,
    int M, bf16* __restrict__ out, int ldo)
{
    __shared__ float As[32][68];
    __shared__ float Bs[32][68];
    int m0 = blockIdx.x * 64;
    int wc = blockIdx.y * 64;
    int tid = threadIdx.x;
    int tx = tid & 15, ty = tid >> 4;
    float acc[4][4] = {};
    for (int k0 = 0; k0 < K; k0 += 32) {
        #pragma unroll
        for (int r = 0; r < 8; r++) {
            int idx = tid + r * 256;          // 64 x 32
            int m = idx >> 5, kk = idx & 31;
            float va = 0.f;
            if (m0 + m < M) va = ldf(&A[(size_t)(m0 + m) * K + k0 + kk]);
            As[kk][m] = va;
        }
        #pragma unroll
        for (int r = 0; r < 8; r++) {
            int idx = tid + r * 256;          // 32 x 64
            int kk = idx >> 6, nn = idx & 63;
            Bs[kk][nn] = W[(size_t)(k0 + kk) * ldw + wc + nn];
        }
        __syncthreads();
        #pragma unroll
        for (int kk = 0; kk < 32; kk++) {
            float a[4], b[4];
            #pragma unroll
            for (int i = 0; i < 4; i++) a[i] = As[kk][ty * 4 + i];
            #pragma unroll
            for (int j = 0; j < 4; j++) b[j] = Bs[kk][tx * 4 + j];
            #pragma unroll
            for (int i = 0; i < 4; i++)
                #pragma unroll
                for (int j = 0; j < 4; j++) acc[i][j] += a[i] * b[j];
        }
        __syncthreads();
    }
    #pragma unroll
    for (int i = 0; i < 4; i++) {
        int m = m0 + ty * 4 + i;
        if (m >= M) continue;
        #pragma unroll
        for (int j = 0; j < 4; j++) {
            int c = wc + tx * 4 + j;
            out[(size_t)m * ldo + c] = __float2bfloat16(acc[i][j] + bias[c]);
        }
    }
}

// ---------------- edge-parallel scores: thread = (edge, head), no LDS, no barriers ----------------
__global__ void __launch_bounds__(256) edge_logits(
    const int* __restrict__ src, const int* __restrict__ dst,
    const float* __restrict__ eattr,
    const u16* __restrict__ qb, const u16* __restrict__ kb,
    const u16* __restrict__ qweb,
    float* __restrict__ alphas, int E)
{
    int t = blockIdx.x * 256 + threadIdx.x;
    if (t >= 4 * E) return;
    int e = t >> 2, h = t & 3;
    int dn = dst[e], sn = src[e];
    const uint4* qp = (const uint4*)(qb + (size_t)dn * HD + (h << 6));
    const uint4* kp = (const uint4*)(kb + (size_t)sn * HD + (h << 6));
    float acc = 0.f;
    #pragma unroll
    for (int i = 0; i < 8; i++) {
        uint4 qa = qp[i], ka = kp[i];
        acc += lo16f(qa.x) * lo16f(ka.x) + hi16f(qa.x) * hi16f(ka.x)
             + lo16f(qa.y) * lo16f(ka.y) + hi16f(qa.y) * hi16f(ka.y)
             + lo16f(qa.z) * lo16f(ka.z) + hi16f(qa.z) * hi16f(ka.z)
             + lo16f(qa.w) * lo16f(ka.w) + hi16f(qa.w) * hi16f(ka.w);
    }
    const uint4*  wp = (const uint4*)(qweb + (size_t)dn * 64 + (h << 4));
    const float4* ep = (const float4*)(eattr + (size_t)e * 16);
    #pragma unroll
    for (int i = 0; i < 2; i++) {
        uint4  wa = wp[i];
        float4 ea = ep[2 * i], eb = ep[2 * i + 1];
        acc += lo16f(wa.x) * ea.x + hi16f(wa.x) * ea.y + lo16f(wa.y) * ea.z + hi16f(wa.y) * ea.w
             + lo16f(wa.z) * eb.x + hi16f(wa.z) * eb.y + lo16f(wa.w) * eb.z + hi16f(wa.w) * eb.w;
    }
    alphas[t] = __expf(acc * 0.125f);    // SCALE = 1/sqrt(64); no max-subtraction (cancels)
}

// ---------------- node-parallel aggregation + epilogue ----------------
// block = node, wave = head, lane = channel. Per edge: alpha broadcast + coalesced v-row + ea.
__global__ void __launch_bounds__(256) node_agg(
    const int* __restrict__ rowptr, const int2* __restrict__ csr2,
    const float* __restrict__ alphas, const float* __restrict__ eattr,
    const u16* __restrict__ vb,
    const float* __restrict__ We,
    const u16* __restrict__ skipb,
    const float* __restrict__ lng, const float* __restrict__ lnb,
    bf16* __restrict__ outB, float* __restrict__ outF)
{
    int n = blockIdx.x;
    int tid = threadIdx.x, w = tid >> 6, lane = tid & 63;
    __shared__ int   sh_src[64], sh_eid[64];
    __shared__ float sv[4][64];
    __shared__ float se[4][16];

    int e0 = rowptr[n], e1 = rowptr[n + 1];
    float accv = 0.f, acce = 0.f, ssum = 0.f;
    for (int base = e0; base < e1; base += 64) {
        int cnt = e1 - base; if (cnt > 64) cnt = 64;
        __syncthreads();
        if (tid < cnt) {
            int2 sp = csr2[base + tid];
            sh_src[tid] = sp.x;
            sh_eid[tid] = sp.y;
        }
        __syncthreads();
        #pragma unroll 2
        for (int i = 0; i < cnt; i++) {
            float a = alphas[(size_t)sh_eid[i] * 4 + w];           // 64-lane broadcast
            u16 vr = vb[(size_t)sh_src[i] * HD + (w << 6) + lane]; // coalesced 128B row seg
            ssum += a;
            accv += a * __uint_as_float((u32)vr << 16);
            if (lane < 16) acce += a * eattr[(size_t)sh_eid[i] * 16 + lane];
        }
    }
    float inv = (ssum > 0.f) ? 1.f / ssum : 0.f;
    sv[w][lane] = accv * inv;
    if (lane < 16) se[w][lane] = acce * inv;
    __syncthreads();

    if (w == 0) {
        int d = lane;
        float val = 0.f;
        #pragma unroll
        for (int hh = 0; hh < 4; hh++) {
            float xv = sv[hh][d];
            #pragma unroll
            for (int j = 0; j < 16; j++) xv += se[hh][j] * We[j * HD + hh * 64 + d];
            val += xv;
        }
        val = val * 0.25f + __uint_as_float((u32)skipb[(size_t)n * 64 + d] << 16);
        float m = val;
        #pragma unroll
        for (int off = 1; off < 64; off <<= 1) m += __shfl_xor(m, off);
        m *= (1.f / 64.f);
        float diff = val - m;
        float vr = diff * diff;
        #pragma unroll
        for (int off = 1; off < 64; off <<= 1) vr += __shfl_xor(vr, off);
        vr *= (1.f / 64.f);
        float y = diff * rsqrtf(vr + 1e-5f) * lng[d] + lnb[d];
        float ge = 0.5f * y * (1.f + erff(y * 0.70710678118654752f));  // exact GELU
        if (outF) outF[(size_t)n * 64 + d] = ge;
        else      outB[(size_t)n * 64 + d] = __float2bfloat16(ge);
    }
}

extern "C" void kernel_launch(void* const* d_in, const int* in_sizes, int n_in,
                              void* d_out, int out_size, void* d_ws, size_t ws_size,
                              hipStream_t stream)
{
    const float* x     = (const float*)d_in[0];
    const int*   eidx  = (const int*)d_in[1];
    const float* eattr = (const float*)d_in[2];
    struct P { const float *Wq,*bq,*Wk,*bk,*Wv,*bv,*We,*Ws,*bs; };
    P p[3];
    for (int l = 0; l < 3; l++) {
        int base = 3 + l * 9;
        p[l].Wq = (const float*)d_in[base + 0]; p[l].bq = (const float*)d_in[base + 1];
        p[l].Wk = (const float*)d_in[base + 2]; p[l].bk = (const float*)d_in[base + 3];
        p[l].Wv = (const float*)d_in[base + 4]; p[l].bv = (const float*)d_in[base + 5];
        p[l].We = (const float*)d_in[base + 6];
        p[l].Ws = (const float*)d_in[base + 7]; p[l].bs = (const float*)d_in[base + 8];
    }
    const float* lng = (const float*)d_in[30];
    const float* lnb = (const float*)d_in[31];

    // Workspace: ~90.3 MB total
    char* ws = (char*)d_ws;
    size_t off = 0;
    auto alloc = [&](size_t bytes) { void* pp = ws + off; off += (bytes + 255) & ~(size_t)255; return pp; };
    int*   rowptr = (int*)  alloc((NNODES + 1) * 4);
    int*   cursor = (int*)  alloc(NNODES * 4);
    int*   deg    = (int*)  alloc(NNODES * 4);
    int2*  csr2   = (int2*) alloc((size_t)NEDGES * 8);
    bf16*  hbuf   = (bf16*) alloc((size_t)NNODES * 64 * 2);
    bf16*  buf_a  = (bf16*) alloc((size_t)NNODES * HD * 2);   // q, then reused for v
    bf16*  buf_b  = (bf16*) alloc((size_t)NNODES * HD * 2);   // k
    bf16*  qweb   = (bf16*) alloc((size_t)NNODES * 64 * 2);
    bf16*  skipb  = (bf16*) alloc((size_t)NNODES * 64 * 2);
    float* alphas = (float*)alloc((size_t)NEDGES * 4 * 4);
    float* wqwe[3];
    int fins[3] = {128, 64, 64};
    for (int l = 0; l < 3; l++) wqwe[l] = (float*)alloc((size_t)(fins[l] + 1) * 64 * 4);

    const int* srcArr = eidx;           // edge_index[0]
    const int* dstArr = eidx + NEDGES;  // edge_index[1]

    // CSR build
    hipMemsetAsync(deg, 0, NNODES * 4, stream);
    hist_kernel<<<(NEDGES + 255) / 256, 256, 0, stream>>>(dstArr, deg, NEDGES);
    scan_kernel<<<1, 1024, 0, stream>>>(deg, rowptr, cursor, NNODES);
    scatter_kernel<<<(NEDGES + 255) / 256, 256, 0, stream>>>(srcArr, dstArr, cursor, csr2, NEDGES);

    // Wq @ We^T folds (per layer)
    for (int l = 0; l < 3; l++)
        wqwe_kernel<<<fins[l] + 1, 64, 0, stream>>>(p[l].Wq, p[l].bq, p[l].We, wqwe[l], fins[l]);

    int gE = (4 * NEDGES + 255) / 256;
    dim3 gm((NNODES + 63) / 64, 4);   // width-256 GEMMs
    dim3 gs((NNODES + 63) / 64, 1);   // width-64 GEMMs

    const void* hin = x;   // layer input (fp32 for l=0, bf16 after)
    for (int l = 0; l < 3; l++) {
        int FIN = fins[l];
        // q -> buf_a, k -> buf_b, skip -> skipb, qwe -> qweb
        if (l == 0) {
            gemm_bias<float><<<gm, 256, 0, stream>>>((const float*)hin, FIN, p[l].Wq, HD, p[l].bq, NNODES, buf_a, HD);
            gemm_bias<float><<<gm, 256, 0, stream>>>((const float*)hin, FIN, p[l].Wk, HD, p[l].bk, NNODES, buf_b, HD);
            gemm_bias<float><<<gs, 256, 0, stream>>>((const float*)hin, FIN, p[l].Ws, 64, p[l].bs, NNODES, skipb, 64);
            gemm_bias<float><<<gs, 256, 0, stream>>>((const float*)hin, FIN, wqwe[l], 64, wqwe[l] + FIN * 64, NNODES, qweb, 64);
        } else {
            gemm_bias<bf16><<<gm, 256, 0, stream>>>((const bf16*)hin, FIN, p[l].Wq, HD, p[l].bq, NNODES, buf_a, HD);
            gemm_bias<bf16><<<gm, 256, 0, stream>>>((const bf16*)hin, FIN, p[l].Wk, HD, p[l].bk, NNODES, buf_b, HD);
            gemm_bias<bf16><<<gs, 256, 0, stream>>>((const bf16*)hin, FIN, p[l].Ws, 64, p[l].bs, NNODES, skipb, 64);
            gemm_bias<bf16><<<gs, 256, 0, stream>>>((const bf16*)hin, FIN, wqwe[l], 64, wqwe[l] + FIN * 64, NNODES, qweb, 64);
        }
        // edge scores (reads buf_a=q, buf_b=k)
        edge_logits<<<gE, 256, 0, stream>>>(srcArr, dstArr, eattr,
            (const u16*)buf_a, (const u16*)buf_b, (const u16*)qweb, alphas, NEDGES);
        // v -> buf_a (overwrites q; safe, stream-ordered after edge_logits)
        if (l == 0) gemm_bias<float><<<gm, 256, 0, stream>>>((const float*)hin, FIN, p[l].Wv, HD, p[l].bv, NNODES, buf_a, HD);
        else        gemm_bias<bf16><<<gm, 256, 0, stream>>>((const bf16*)hin, FIN, p[l].Wv, HD, p[l].bv, NNODES, buf_a, HD);
        // aggregate + epilogue
        node_agg<<<NNODES, 256, 0, stream>>>(rowptr, csr2, alphas, eattr,
            (const u16*)buf_a, p[l].We, (const u16*)skipb, lng, lnb,
            (l == 2) ? nullptr : hbuf, (l == 2) ? (float*)d_out : nullptr);
        hin = hbuf;
    }
}

// Round 7
// 1871.344 us; speedup vs baseline: 2.5244x; 1.3500x over previous
//
#include <hip/hip_runtime.h>
#include <hip/hip_bf16.h>
#include <math.h>

#define NNODES 50000
#define NEDGES 800000
#define HD     256   // HEADS*DHEAD
#define CW     576   // combined buffer width: q(256)|k(256)|qwe(64); pass2: v(256)|skip(64)

typedef __hip_bfloat16 bf16;
typedef unsigned short u16;
typedef unsigned int   u32;
typedef __attribute__((ext_vector_type(8))) short bf16x8;
typedef __attribute__((ext_vector_type(4))) float f32x4;

__device__ __forceinline__ float b2f(bf16 v) { return __bfloat162float(v); }
__device__ __forceinline__ float ldf(const float* p) { return *p; }
__device__ __forceinline__ float ldf(const bf16* p)  { return __bfloat162float(*p); }
__device__ __forceinline__ float lo16f(u32 u) { return __uint_as_float(u << 16); }
__device__ __forceinline__ float hi16f(u32 u) { return __uint_as_float(u & 0xFFFF0000u); }
__device__ __forceinline__ short f2s(float v) { __hip_bfloat16 h = __float2bfloat16(v); return *(short*)&h; }

// ---------------- CSR build ----------------
__global__ void hist_kernel(const int* __restrict__ dst, int* __restrict__ deg, int E) {
    int e = blockIdx.x * 256 + threadIdx.x;
    if (e < E) atomicAdd(&deg[dst[e]], 1);
}

__global__ void scan_kernel(const int* __restrict__ deg, int* __restrict__ rowptr,
                            int* __restrict__ cursor, int n) {
    __shared__ int sh[1024];
    int running = 0;
    for (int base = 0; base < n; base += 1024) {
        int i = base + threadIdx.x;
        int d = (i < n) ? deg[i] : 0;
        sh[threadIdx.x] = d;
        __syncthreads();
        for (int off = 1; off < 1024; off <<= 1) {
            int t = (threadIdx.x >= (unsigned)off) ? sh[threadIdx.x - off] : 0;
            __syncthreads();
            sh[threadIdx.x] += t;
            __syncthreads();
        }
        int incl = sh[threadIdx.x];
        int tot  = sh[1023];
        __syncthreads();
        if (i < n) {
            int ex = running + incl - d;
            rowptr[i] = ex;
            cursor[i] = ex;
        }
        running += tot;
    }
    if (threadIdx.x == 0) rowptr[n] = running;
}

__global__ void scatter_kernel(const int* __restrict__ src, const int* __restrict__ dst,
                               int* __restrict__ cursor, int2* __restrict__ csr2, int E) {
    int e = blockIdx.x * 256 + threadIdx.x;
    if (e < E) {
        int p = atomicAdd(&cursor[dst[e]], 1);
        csr2[p] = make_int2(src[e], e);
    }
}

// WqWe[c][h*16+j] = sum_d Wq[c, h*64+d] * We[j, h*64+d]; row c==FIN is the bq-derived bias.
__global__ void wqwe_kernel(const float* __restrict__ Wq, const float* __restrict__ bq,
                            const float* __restrict__ We, float* __restrict__ out, int FIN) {
    int c = blockIdx.x;              // 0..FIN inclusive
    int t = threadIdx.x;             // h = t>>4, j = t&15
    int h = t >> 4, j = t & 15;
    const float* qrow = (c == FIN) ? bq : (Wq + (size_t)c * HD);
    float s = 0.f;
    #pragma unroll 8
    for (int d = 0; d < 64; d++) s += qrow[h * 64 + d] * We[j * HD + h * 64 + d];
    out[c * 64 + t] = s;
}

// ---- weight packs: n-major bf16 [N][K] + fp32 bias ----
__global__ void pack1(const float* __restrict__ Wq, const float* __restrict__ bq,
                      const float* __restrict__ Wk, const float* __restrict__ bk,
                      const float* __restrict__ wqwe,
                      bf16* __restrict__ Wc, float* __restrict__ b, int K) {
    int n = blockIdx.x, c = threadIdx.x;   // blockDim = K
    float v;
    if (n < 256)      v = Wq[(size_t)c * 256 + n];
    else if (n < 512) v = Wk[(size_t)c * 256 + n - 256];
    else              v = wqwe[c * 64 + n - 512];
    Wc[(size_t)n * K + c] = __float2bfloat16(v);
    if (c == 0) b[n] = (n < 256) ? bq[n] : (n < 512 ? bk[n - 256] : wqwe[K * 64 + n - 512]);
}

__global__ void pack2(const float* __restrict__ Wv, const float* __restrict__ bv,
                      const float* __restrict__ Ws, const float* __restrict__ bs,
                      bf16* __restrict__ Wc, float* __restrict__ b, int K) {
    int n = blockIdx.x, c = threadIdx.x;
    float v = (n < 256) ? Wv[(size_t)c * 256 + n] : Ws[(size_t)c * 64 + n - 256];
    Wc[(size_t)n * K + c] = __float2bfloat16(v);
    if (c == 0) b[n] = (n < 256) ? bv[n] : bs[n - 256];
}

// ---------------- MFMA bf16 GEMM: out[M x ldo] = A[M x K] @ Wc^T + bias ----------------
// Wc is n-major [N][K] bf16. Block = 64(m) x 64(n) tile, 4 waves (wave w = rows w*16..+15).
template<typename TA>
__global__ void __launch_bounds__(256) gemm_mfma(
    const TA* __restrict__ A, int K,
    const bf16* __restrict__ Wc, const float* __restrict__ bias,
    int M, bf16* __restrict__ out, int ldo)
{
    __shared__ short Al[64 * 40];   // [row][k], stride 40 breaks frag-read bank conflicts
    __shared__ short Bl[64 * 40];   // [n][k]
    int m0 = blockIdx.x * 64, n0 = blockIdx.y * 64;
    int tid = threadIdx.x;
    int w = tid >> 6, lane = tid & 63;
    int lr = tid >> 2, lc = (tid & 3) * 8;         // staging coords: 8 bf16 per thread
    f32x4 acc[4] = {};

    for (int k0 = 0; k0 < K; k0 += 32) {
        __syncthreads();
        // stage A (zero-pad rows >= M)
        {
            int m = m0 + lr;
            uint4 val = make_uint4(0, 0, 0, 0);
            if (m < M) {
                if constexpr (sizeof(TA) == 4) {   // fp32 input -> cvt to bf16
                    const float4* ap = (const float4*)((const float*)A + (size_t)m * K + k0 + lc);
                    float4 f0 = ap[0], f1 = ap[1];
                    union { short s[8]; uint4 u; } t;
                    t.s[0] = f2s(f0.x); t.s[1] = f2s(f0.y); t.s[2] = f2s(f0.z); t.s[3] = f2s(f0.w);
                    t.s[4] = f2s(f1.x); t.s[5] = f2s(f1.y); t.s[6] = f2s(f1.z); t.s[7] = f2s(f1.w);
                    val = t.u;
                } else {
                    val = *(const uint4*)((const u16*)A + (size_t)m * K + k0 + lc);
                }
            }
            *(uint4*)&Al[lr * 40 + lc] = val;
        }
        // stage B
        *(uint4*)&Bl[lr * 40 + lc] = *(const uint4*)((const u16*)Wc + (size_t)(n0 + lr) * K + k0 + lc);
        __syncthreads();

        int am = lane & 15, aq = lane >> 4;
        bf16x8 af = *(const bf16x8*)&Al[(w * 16 + am) * 40 + aq * 8];
        #pragma unroll
        for (int t = 0; t < 4; t++) {
            bf16x8 bfr = *(const bf16x8*)&Bl[(t * 16 + am) * 40 + aq * 8];
            acc[t] = __builtin_amdgcn_mfma_f32_16x16x32_bf16(af, bfr, acc[t], 0, 0, 0);
        }
    }
    // epilogue: D mapping col=lane&15, row=(lane>>4)*4+reg
    int cl = lane & 15, rq = lane >> 4;
    #pragma unroll
    for (int t = 0; t < 4; t++) {
        int c = n0 + t * 16 + cl;
        float bv = bias[c];
        #pragma unroll
        for (int r = 0; r < 4; r++) {
            int m = m0 + w * 16 + rq * 4 + r;
            if (m < M) out[(size_t)m * ldo + c] = __float2bfloat16(acc[t][r] + bv);
        }
    }
}

// ---------------- edge-parallel scores: thread = (edge, head) ----------------
// comb row layout (u16, stride 576): q 0-255 | k 256-511 | qwe 512-575
__global__ void __launch_bounds__(256) edge_logits(
    const int* __restrict__ src, const int* __restrict__ dst,
    const float* __restrict__ eattr, const u16* __restrict__ comb,
    float* __restrict__ alphas, int E)
{
    int t = blockIdx.x * 256 + threadIdx.x;
    if (t >= 4 * E) return;
    int e = t >> 2, h = t & 3;
    int dn = dst[e], sn = src[e];
    const uint4* qp = (const uint4*)(comb + (size_t)dn * CW + (h << 6));
    const uint4* kp = (const uint4*)(comb + (size_t)sn * CW + 256 + (h << 6));
    float acc = 0.f;
    #pragma unroll
    for (int i = 0; i < 8; i++) {
        uint4 qa = qp[i], ka = kp[i];
        acc += lo16f(qa.x) * lo16f(ka.x) + hi16f(qa.x) * hi16f(ka.x)
             + lo16f(qa.y) * lo16f(ka.y) + hi16f(qa.y) * hi16f(ka.y)
             + lo16f(qa.z) * lo16f(ka.z) + hi16f(qa.z) * hi16f(ka.z)
             + lo16f(qa.w) * lo16f(ka.w) + hi16f(qa.w) * hi16f(ka.w);
    }
    const uint4*  wp = (const uint4*)(comb + (size_t)dn * CW + 512 + (h << 4));
    const float4* ep = (const float4*)(eattr + (size_t)e * 16);
    #pragma unroll
    for (int i = 0; i < 2; i++) {
        uint4  wa = wp[i];
        float4 ea = ep[2 * i], eb = ep[2 * i + 1];
        acc += lo16f(wa.x) * ea.x + hi16f(wa.x) * ea.y + lo16f(wa.y) * ea.z + hi16f(wa.y) * ea.w
             + lo16f(wa.z) * eb.x + hi16f(wa.z) * eb.y + lo16f(wa.w) * eb.z + hi16f(wa.w) * eb.w;
    }
    alphas[t] = __expf(acc * 0.125f);   // SCALE=1/8; max-subtraction cancels exactly
}

// ---------------- node aggregation + epilogue ----------------
// block = node, wave = head, lane = channel. 4-deep software pipeline (4 acc tuples).
// comb after pass2: v 0-255 | skip 256-319
__global__ void __launch_bounds__(256) node_agg(
    const int* __restrict__ rowptr, const int2* __restrict__ csr2,
    const float* __restrict__ alphas, const float* __restrict__ eattr,
    const u16* __restrict__ comb, const float* __restrict__ We,
    const float* __restrict__ lng, const float* __restrict__ lnb,
    bf16* __restrict__ outB, float* __restrict__ outF)
{
    int n = blockIdx.x;
    int tid = threadIdx.x, w = tid >> 6, lane = tid & 63;
    __shared__ int   sh_src[64], sh_eid[64];
    __shared__ float sv[4][64];
    __shared__ float se[4][16];

    int e0 = rowptr[n], e1 = rowptr[n + 1];
    float av0 = 0.f, av1 = 0.f, av2 = 0.f, av3 = 0.f;
    float ae0 = 0.f, ae1 = 0.f, ae2 = 0.f, ae3 = 0.f;
    float ss0 = 0.f, ss1 = 0.f, ss2 = 0.f, ss3 = 0.f;
    int voff = (w << 6) + lane;

    for (int base = e0; base < e1; base += 64) {
        int cnt = e1 - base; if (cnt > 64) cnt = 64;
        __syncthreads();
        if (tid < cnt) {
            int2 sp = csr2[base + tid];
            sh_src[tid] = sp.x;
            sh_eid[tid] = sp.y;
        }
        __syncthreads();
        int i = 0;
        for (; i + 4 <= cnt; i += 4) {
            int s0 = sh_src[i], s1 = sh_src[i+1], s2 = sh_src[i+2], s3 = sh_src[i+3];
            int q0 = sh_eid[i], q1 = sh_eid[i+1], q2 = sh_eid[i+2], q3 = sh_eid[i+3];
            float a0 = alphas[(size_t)q0 * 4 + w];
            float a1 = alphas[(size_t)q1 * 4 + w];
            float a2 = alphas[(size_t)q2 * 4 + w];
            float a3 = alphas[(size_t)q3 * 4 + w];
            u16 r0 = comb[(size_t)s0 * CW + voff];
            u16 r1 = comb[(size_t)s1 * CW + voff];
            u16 r2 = comb[(size_t)s2 * CW + voff];
            u16 r3 = comb[(size_t)s3 * CW + voff];
            float e0v = 0.f, e1v = 0.f, e2v = 0.f, e3v = 0.f;
            if (lane < 16) {
                e0v = eattr[(size_t)q0 * 16 + lane];
                e1v = eattr[(size_t)q1 * 16 + lane];
                e2v = eattr[(size_t)q2 * 16 + lane];
                e3v = eattr[(size_t)q3 * 16 + lane];
            }
            ss0 += a0; av0 += a0 * __uint_as_float((u32)r0 << 16); ae0 += a0 * e0v;
            ss1 += a1; av1 += a1 * __uint_as_float((u32)r1 << 16); ae1 += a1 * e1v;
            ss2 += a2; av2 += a2 * __uint_as_float((u32)r2 << 16); ae2 += a2 * e2v;
            ss3 += a3; av3 += a3 * __uint_as_float((u32)r3 << 16); ae3 += a3 * e3v;
        }
        for (; i < cnt; i++) {
            int s0 = sh_src[i], q0 = sh_eid[i];
            float a0 = alphas[(size_t)q0 * 4 + w];
            u16 r0 = comb[(size_t)s0 * CW + voff];
            float e0v = (lane < 16) ? eattr[(size_t)q0 * 16 + lane] : 0.f;
            ss0 += a0; av0 += a0 * __uint_as_float((u32)r0 << 16); ae0 += a0 * e0v;
        }
    }
    float ssum = (ss0 + ss1) + (ss2 + ss3);
    float accv = (av0 + av1) + (av2 + av3);
    float acce = (ae0 + ae1) + (ae2 + ae3);
    float inv = (ssum > 0.f) ? 1.f / ssum : 0.f;
    sv[w][lane] = accv * inv;
    if (lane < 16) se[w][lane] = acce * inv;
    __syncthreads();

    if (w == 0) {
        int d = lane;
        float val = 0.f;
        #pragma unroll
        for (int hh = 0; hh < 4; hh++) {
            float xv = sv[hh][d];
            #pragma unroll
            for (int j = 0; j < 16; j++) xv += se[hh][j] * We[j * HD + hh * 64 + d];
            val += xv;
        }
        val = val * 0.25f + __uint_as_float((u32)comb[(size_t)n * CW + 256 + d] << 16);
        float m = val;
        #pragma unroll
        for (int off = 1; off < 64; off <<= 1) m += __shfl_xor(m, off);
        m *= (1.f / 64.f);
        float diff = val - m;
        float vr = diff * diff;
        #pragma unroll
        for (int off = 1; off < 64; off <<= 1) vr += __shfl_xor(vr, off);
        vr *= (1.f / 64.f);
        float y = diff * rsqrtf(vr + 1e-5f) * lng[d] + lnb[d];
        float ge = 0.5f * y * (1.f + erff(y * 0.70710678118654752f));   // exact GELU
        if (outF) outF[(size_t)n * 64 + d] = ge;
        else      outB[(size_t)n * 64 + d] = __float2bfloat16(ge);
    }
}

extern "C" void kernel_launch(void* const* d_in, const int* in_sizes, int n_in,
                              void* d_out, int out_size, void* d_ws, size_t ws_size,
                              hipStream_t stream)
{
    const float* x     = (const float*)d_in[0];
    const int*   eidx  = (const int*)d_in[1];
    const float* eattr = (const float*)d_in[2];
    struct P { const float *Wq,*bq,*Wk,*bk,*Wv,*bv,*We,*Ws,*bs; };
    P p[3];
    for (int l = 0; l < 3; l++) {
        int base = 3 + l * 9;
        p[l].Wq = (const float*)d_in[base + 0]; p[l].bq = (const float*)d_in[base + 1];
        p[l].Wk = (const float*)d_in[base + 2]; p[l].bk = (const float*)d_in[base + 3];
        p[l].Wv = (const float*)d_in[base + 4]; p[l].bv = (const float*)d_in[base + 5];
        p[l].We = (const float*)d_in[base + 6];
        p[l].Ws = (const float*)d_in[base + 7]; p[l].bs = (const float*)d_in[base + 8];
    }
    const float* lng = (const float*)d_in[30];
    const float* lnb = (const float*)d_in[31];

    // Workspace: ~84 MB
    char* ws = (char*)d_ws;
    size_t off = 0;
    auto alloc = [&](size_t bytes) { void* pp = ws + off; off += (bytes + 255) & ~(size_t)255; return pp; };
    int*   rowptr = (int*)  alloc((NNODES + 1) * 4);
    int*   cursor = (int*)  alloc(NNODES * 4);
    int*   deg    = (int*)  alloc(NNODES * 4);
    int2*  csr2   = (int2*) alloc((size_t)NEDGES * 8);
    bf16*  hbuf   = (bf16*) alloc((size_t)NNODES * 64 * 2);
    bf16*  comb   = (bf16*) alloc((size_t)NNODES * CW * 2);   // 57.6 MB
    float* alphas = (float*)alloc((size_t)NEDGES * 4 * 4);    // 12.8 MB
    float* wqwe   = (float*)alloc((size_t)129 * 64 * 4);      // reused per layer
    bf16*  Wc1    = (bf16*) alloc((size_t)CW * 128 * 2);
    bf16*  Wc2    = (bf16*) alloc((size_t)320 * 128 * 2);
    float* b1     = (float*)alloc(CW * 4);
    float* b2     = (float*)alloc(320 * 4);

    const int* srcArr = eidx;           // edge_index[0]
    const int* dstArr = eidx + NEDGES;  // edge_index[1]

    // CSR build
    hipMemsetAsync(deg, 0, NNODES * 4, stream);
    hist_kernel<<<(NEDGES + 255) / 256, 256, 0, stream>>>(dstArr, deg, NEDGES);
    scan_kernel<<<1, 1024, 0, stream>>>(deg, rowptr, cursor, NNODES);
    scatter_kernel<<<(NEDGES + 255) / 256, 256, 0, stream>>>(srcArr, dstArr, cursor, csr2, NEDGES);

    int gE = (4 * NEDGES + 255) / 256;
    int gm = (NNODES + 63) / 64;
    int fins[3] = {128, 64, 64};

    const void* hin = x;
    for (int l = 0; l < 3; l++) {
        int FIN = fins[l];
        // fold Wq@We^T (+bias row), pack weights
        wqwe_kernel<<<FIN + 1, 64, 0, stream>>>(p[l].Wq, p[l].bq, p[l].We, wqwe, FIN);
        pack1<<<CW, FIN, 0, stream>>>(p[l].Wq, p[l].bq, p[l].Wk, p[l].bk, wqwe, Wc1, b1, FIN);
        pack2<<<320, FIN, 0, stream>>>(p[l].Wv, p[l].bv, p[l].Ws, p[l].bs, Wc2, b2, FIN);
        // pass1: q|k|qwe
        if (l == 0) gemm_mfma<float><<<dim3(gm, 9), 256, 0, stream>>>((const float*)hin, FIN, Wc1, b1, NNODES, comb, CW);
        else        gemm_mfma<bf16> <<<dim3(gm, 9), 256, 0, stream>>>((const bf16*)hin,  FIN, Wc1, b1, NNODES, comb, CW);
        // edge scores
        edge_logits<<<gE, 256, 0, stream>>>(srcArr, dstArr, eattr, (const u16*)comb, alphas, NEDGES);
        // pass2: v|skip (overwrites q/k region after edge_logits; stream-ordered)
        if (l == 0) gemm_mfma<float><<<dim3(gm, 5), 256, 0, stream>>>((const float*)hin, FIN, Wc2, b2, NNODES, comb, CW);
        else        gemm_mfma<bf16> <<<dim3(gm, 5), 256, 0, stream>>>((const bf16*)hin,  FIN, Wc2, b2, NNODES, comb, CW);
        // aggregate + LN + GELU
        node_agg<<<NNODES, 256, 0, stream>>>(rowptr, csr2, alphas, eattr, (const u16*)comb,
            p[l].We, lng, lnb, (l == 2) ? nullptr : hbuf, (l == 2) ? (float*)d_out : nullptr);
        hin = hbuf;
    }
}

// Round 8
// 1430.808 us; speedup vs baseline: 3.3017x; 1.3079x over previous
//
#include <hip/hip_runtime.h>
#include <hip/hip_bf16.h>
#include <math.h>

#define NNODES 50000
#define NEDGES 800000
#define HD     256   // HEADS*DHEAD
#define CW     576   // combined buffer width: q(256)|k(256)|qwe(64); pass2: v(256)|skip(64)

typedef __hip_bfloat16 bf16;
typedef unsigned short u16;
typedef unsigned int   u32;
typedef __attribute__((ext_vector_type(8))) short bf16x8;
typedef __attribute__((ext_vector_type(4))) float f32x4;

__device__ __forceinline__ float b2f(bf16 v) { return __bfloat162float(v); }
__device__ __forceinline__ float ldf(const float* p) { return *p; }
__device__ __forceinline__ float ldf(const bf16* p)  { return __bfloat162float(*p); }
__device__ __forceinline__ float lo16f(u32 u) { return __uint_as_float(u << 16); }
__device__ __forceinline__ float hi16f(u32 u) { return __uint_as_float(u & 0xFFFF0000u); }
__device__ __forceinline__ short f2s(float v) { __hip_bfloat16 h = __float2bfloat16(v); return *(short*)&h; }

// ---------------- CSR build ----------------
__global__ void hist_kernel(const int* __restrict__ dst, int* __restrict__ deg, int E) {
    int e = blockIdx.x * 256 + threadIdx.x;
    if (e < E) atomicAdd(&deg[dst[e]], 1);
}

__global__ void scan_kernel(const int* __restrict__ deg, int* __restrict__ rowptr,
                            int* __restrict__ cursor, int n) {
    __shared__ int sh[1024];
    int running = 0;
    for (int base = 0; base < n; base += 1024) {
        int i = base + threadIdx.x;
        int d = (i < n) ? deg[i] : 0;
        sh[threadIdx.x] = d;
        __syncthreads();
        for (int off = 1; off < 1024; off <<= 1) {
            int t = (threadIdx.x >= (unsigned)off) ? sh[threadIdx.x - off] : 0;
            __syncthreads();
            sh[threadIdx.x] += t;
            __syncthreads();
        }
        int incl = sh[threadIdx.x];
        int tot  = sh[1023];
        __syncthreads();
        if (i < n) {
            int ex = running + incl - d;
            rowptr[i] = ex;
            cursor[i] = ex;
        }
        running += tot;
    }
    if (threadIdx.x == 0) rowptr[n] = running;
}

__global__ void scatter_kernel(const int* __restrict__ src, const int* __restrict__ dst,
                               int* __restrict__ cursor, int4* __restrict__ csr4, int E) {
    int e = blockIdx.x * 256 + threadIdx.x;
    if (e < E) {
        int d = dst[e];
        int p = atomicAdd(&cursor[d], 1);
        csr4[p] = make_int4(src[e], e, d, 0);
    }
}

// WqWe[c][h*16+j] = sum_d Wq[c, h*64+d] * We[j, h*64+d]; row c==FIN is the bq-derived bias.
__global__ void wqwe_kernel(const float* __restrict__ Wq, const float* __restrict__ bq,
                            const float* __restrict__ We, float* __restrict__ out, int FIN) {
    int c = blockIdx.x;              // 0..FIN inclusive
    int t = threadIdx.x;             // h = t>>4, j = t&15
    int h = t >> 4, j = t & 15;
    const float* qrow = (c == FIN) ? bq : (Wq + (size_t)c * HD);
    float s = 0.f;
    #pragma unroll 8
    for (int d = 0; d < 64; d++) s += qrow[h * 64 + d] * We[j * HD + h * 64 + d];
    out[c * 64 + t] = s;
}

// ---- weight packs: n-major bf16 [N][K] + fp32 bias ----
__global__ void pack1(const float* __restrict__ Wq, const float* __restrict__ bq,
                      const float* __restrict__ Wk, const float* __restrict__ bk,
                      const float* __restrict__ wqwe,
                      bf16* __restrict__ Wc, float* __restrict__ b, int K) {
    int n = blockIdx.x, c = threadIdx.x;   // blockDim = K
    float v;
    if (n < 256)      v = Wq[(size_t)c * 256 + n];
    else if (n < 512) v = Wk[(size_t)c * 256 + n - 256];
    else              v = wqwe[c * 64 + n - 512];
    Wc[(size_t)n * K + c] = __float2bfloat16(v);
    if (c == 0) b[n] = (n < 256) ? bq[n] : (n < 512 ? bk[n - 256] : wqwe[K * 64 + n - 512]);
}

__global__ void pack2(const float* __restrict__ Wv, const float* __restrict__ bv,
                      const float* __restrict__ Ws, const float* __restrict__ bs,
                      bf16* __restrict__ Wc, float* __restrict__ b, int K) {
    int n = blockIdx.x, c = threadIdx.x;
    float v = (n < 256) ? Wv[(size_t)c * 256 + n] : Ws[(size_t)c * 64 + n - 256];
    Wc[(size_t)n * K + c] = __float2bfloat16(v);
    if (c == 0) b[n] = (n < 256) ? bv[n] : bs[n - 256];
}

// ---------------- MFMA bf16 GEMM: out[M x ldo] = A[M x K] @ Wc^T + bias ----------------
template<typename TA>
__global__ void __launch_bounds__(256) gemm_mfma(
    const TA* __restrict__ A, int K,
    const bf16* __restrict__ Wc, const float* __restrict__ bias,
    int M, bf16* __restrict__ out, int ldo)
{
    __shared__ short Al[64 * 40];   // stride 40 breaks frag-read bank conflicts
    __shared__ short Bl[64 * 40];
    int m0 = blockIdx.x * 64, n0 = blockIdx.y * 64;
    int tid = threadIdx.x;
    int w = tid >> 6, lane = tid & 63;
    int lr = tid >> 2, lc = (tid & 3) * 8;
    f32x4 acc[4] = {};

    for (int k0 = 0; k0 < K; k0 += 32) {
        __syncthreads();
        {
            int m = m0 + lr;
            uint4 val = make_uint4(0, 0, 0, 0);
            if (m < M) {
                if constexpr (sizeof(TA) == 4) {
                    const float4* ap = (const float4*)((const float*)A + (size_t)m * K + k0 + lc);
                    float4 f0 = ap[0], f1 = ap[1];
                    union { short s[8]; uint4 u; } t;
                    t.s[0] = f2s(f0.x); t.s[1] = f2s(f0.y); t.s[2] = f2s(f0.z); t.s[3] = f2s(f0.w);
                    t.s[4] = f2s(f1.x); t.s[5] = f2s(f1.y); t.s[6] = f2s(f1.z); t.s[7] = f2s(f1.w);
                    val = t.u;
                } else {
                    val = *(const uint4*)((const u16*)A + (size_t)m * K + k0 + lc);
                }
            }
            *(uint4*)&Al[lr * 40 + lc] = val;
        }
        *(uint4*)&Bl[lr * 40 + lc] = *(const uint4*)((const u16*)Wc + (size_t)(n0 + lr) * K + k0 + lc);
        __syncthreads();

        int am = lane & 15, aq = lane >> 4;
        bf16x8 af = *(const bf16x8*)&Al[(w * 16 + am) * 40 + aq * 8];
        #pragma unroll
        for (int t = 0; t < 4; t++) {
            bf16x8 bfr = *(const bf16x8*)&Bl[(t * 16 + am) * 40 + aq * 8];
            acc[t] = __builtin_amdgcn_mfma_f32_16x16x32_bf16(af, bfr, acc[t], 0, 0, 0);
        }
    }
    int cl = lane & 15, rq = lane >> 4;
    #pragma unroll
    for (int t = 0; t < 4; t++) {
        int c = n0 + t * 16 + cl;
        float bv = bias[c];
        #pragma unroll
        for (int r = 0; r < 4; r++) {
            int m = m0 + w * 16 + rq * 4 + r;
            if (m < M) out[(size_t)m * ldo + c] = __float2bfloat16(acc[t][r] + bv);
        }
    }
}

// ---------------- edge scores in CSR (dst-major) order: thread = (csr_pos, head) ----------------
// Consecutive positions share dst -> q/qwe reads are L1/L2 hits; alphas written sequentially.
__global__ void __launch_bounds__(256) edge_logits(
    const int4* __restrict__ csr4, const float* __restrict__ eattr,
    const u16* __restrict__ comb, float* __restrict__ alphas, int E)
{
    int t = blockIdx.x * 256 + threadIdx.x;
    if (t >= 4 * E) return;
    int pos = t >> 2, h = t & 3;
    int4 c4 = csr4[pos];                 // 4 adjacent threads: same 16B (L1 broadcast)
    int sn = c4.x, eid = c4.y, dn = c4.z;
    const uint4* qp = (const uint4*)(comb + (size_t)dn * CW + (h << 6));
    const uint4* kp = (const uint4*)(comb + (size_t)sn * CW + 256 + (h << 6));
    float acc = 0.f;
    #pragma unroll
    for (int i = 0; i < 8; i++) {
        uint4 qa = qp[i], ka = kp[i];
        acc += lo16f(qa.x) * lo16f(ka.x) + hi16f(qa.x) * hi16f(ka.x)
             + lo16f(qa.y) * lo16f(ka.y) + hi16f(qa.y) * hi16f(ka.y)
             + lo16f(qa.z) * lo16f(ka.z) + hi16f(qa.z) * hi16f(ka.z)
             + lo16f(qa.w) * lo16f(ka.w) + hi16f(qa.w) * hi16f(ka.w);
    }
    const uint4*  wp = (const uint4*)(comb + (size_t)dn * CW + 512 + (h << 4));
    const float4* ep = (const float4*)(eattr + (size_t)eid * 16);
    #pragma unroll
    for (int i = 0; i < 2; i++) {
        uint4  wa = wp[i];
        float4 ea = ep[2 * i], eb = ep[2 * i + 1];
        acc += lo16f(wa.x) * ea.x + hi16f(wa.x) * ea.y + lo16f(wa.y) * ea.z + hi16f(wa.y) * ea.w
             + lo16f(wa.z) * eb.x + hi16f(wa.z) * eb.y + lo16f(wa.w) * eb.z + hi16f(wa.w) * eb.w;
    }
    alphas[t] = __expf(acc * 0.125f);    // SCALE=1/8; max-subtraction cancels exactly
}

// ---------------- node aggregation + epilogue ----------------
// block = node, wave = head, lane = channel. 4-deep pipeline; alphas read sequentially (CSR order).
__global__ void __launch_bounds__(256) node_agg(
    const int* __restrict__ rowptr, const int4* __restrict__ csr4,
    const float* __restrict__ alphas, const float* __restrict__ eattr,
    const u16* __restrict__ comb, const float* __restrict__ We,
    const float* __restrict__ lng, const float* __restrict__ lnb,
    bf16* __restrict__ outB, float* __restrict__ outF)
{
    int n = blockIdx.x;
    int tid = threadIdx.x, w = tid >> 6, lane = tid & 63;
    __shared__ int   sh_src[64], sh_eid[64];
    __shared__ float sv[4][64];
    __shared__ float se[4][16];

    int e0 = rowptr[n], e1 = rowptr[n + 1];
    float av0 = 0.f, av1 = 0.f, av2 = 0.f, av3 = 0.f;
    float ae0 = 0.f, ae1 = 0.f, ae2 = 0.f, ae3 = 0.f;
    float ss0 = 0.f, ss1 = 0.f, ss2 = 0.f, ss3 = 0.f;
    int voff = (w << 6) + lane;

    for (int base = e0; base < e1; base += 64) {
        int cnt = e1 - base; if (cnt > 64) cnt = 64;
        __syncthreads();
        if (tid < cnt) {
            int4 c4 = csr4[base + tid];
            sh_src[tid] = c4.x;
            sh_eid[tid] = c4.y;
        }
        __syncthreads();
        int i = 0;
        for (; i + 4 <= cnt; i += 4) {
            int s0 = sh_src[i], s1 = sh_src[i+1], s2 = sh_src[i+2], s3 = sh_src[i+3];
            int q0 = sh_eid[i], q1 = sh_eid[i+1], q2 = sh_eid[i+2], q3 = sh_eid[i+3];
            size_t p = (size_t)(base + i) * 4 + w;
            float a0 = alphas[p], a1 = alphas[p + 4], a2 = alphas[p + 8], a3 = alphas[p + 12];
            u16 r0 = comb[(size_t)s0 * CW + voff];
            u16 r1 = comb[(size_t)s1 * CW + voff];
            u16 r2 = comb[(size_t)s2 * CW + voff];
            u16 r3 = comb[(size_t)s3 * CW + voff];
            float e0v = 0.f, e1v = 0.f, e2v = 0.f, e3v = 0.f;
            if (lane < 16) {
                e0v = eattr[(size_t)q0 * 16 + lane];
                e1v = eattr[(size_t)q1 * 16 + lane];
                e2v = eattr[(size_t)q2 * 16 + lane];
                e3v = eattr[(size_t)q3 * 16 + lane];
            }
            ss0 += a0; av0 += a0 * __uint_as_float((u32)r0 << 16); ae0 += a0 * e0v;
            ss1 += a1; av1 += a1 * __uint_as_float((u32)r1 << 16); ae1 += a1 * e1v;
            ss2 += a2; av2 += a2 * __uint_as_float((u32)r2 << 16); ae2 += a2 * e2v;
            ss3 += a3; av3 += a3 * __uint_as_float((u32)r3 << 16); ae3 += a3 * e3v;
        }
        for (; i < cnt; i++) {
            int s0 = sh_src[i], q0 = sh_eid[i];
            float a0 = alphas[(size_t)(base + i) * 4 + w];
            u16 r0 = comb[(size_t)s0 * CW + voff];
            float e0v = (lane < 16) ? eattr[(size_t)q0 * 16 + lane] : 0.f;
            ss0 += a0; av0 += a0 * __uint_as_float((u32)r0 << 16); ae0 += a0 * e0v;
        }
    }
    float ssum = (ss0 + ss1) + (ss2 + ss3);
    float accv = (av0 + av1) + (av2 + av3);
    float acce = (ae0 + ae1) + (ae2 + ae3);
    float inv = (ssum > 0.f) ? 1.f / ssum : 0.f;
    sv[w][lane] = accv * inv;
    if (lane < 16) se[w][lane] = acce * inv;
    __syncthreads();

    if (w == 0) {
        int d = lane;
        float val = 0.f;
        #pragma unroll
        for (int hh = 0; hh < 4; hh++) {
            float xv = sv[hh][d];
            #pragma unroll
            for (int j = 0; j < 16; j++) xv += se[hh][j] * We[j * HD + hh * 64 + d];
            val += xv;
        }
        val = val * 0.25f + __uint_as_float((u32)comb[(size_t)n * CW + 256 + d] << 16);
        float m = val;
        #pragma unroll
        for (int off = 1; off < 64; off <<= 1) m += __shfl_xor(m, off);
        m *= (1.f / 64.f);
        float diff = val - m;
        float vr = diff * diff;
        #pragma unroll
        for (int off = 1; off < 64; off <<= 1) vr += __shfl_xor(vr, off);
        vr *= (1.f / 64.f);
        float y = diff * rsqrtf(vr + 1e-5f) * lng[d] + lnb[d];
        float ge = 0.5f * y * (1.f + erff(y * 0.70710678118654752f));   // exact GELU
        if (outF) outF[(size_t)n * 64 + d] = ge;
        else      outB[(size_t)n * 64 + d] = __float2bfloat16(ge);
    }
}

extern "C" void kernel_launch(void* const* d_in, const int* in_sizes, int n_in,
                              void* d_out, int out_size, void* d_ws, size_t ws_size,
                              hipStream_t stream)
{
    const float* x     = (const float*)d_in[0];
    const int*   eidx  = (const int*)d_in[1];
    const float* eattr = (const float*)d_in[2];
    struct P { const float *Wq,*bq,*Wk,*bk,*Wv,*bv,*We,*Ws,*bs; };
    P p[3];
    for (int l = 0; l < 3; l++) {
        int base = 3 + l * 9;
        p[l].Wq = (const float*)d_in[base + 0]; p[l].bq = (const float*)d_in[base + 1];
        p[l].Wk = (const float*)d_in[base + 2]; p[l].bk = (const float*)d_in[base + 3];
        p[l].Wv = (const float*)d_in[base + 4]; p[l].bv = (const float*)d_in[base + 5];
        p[l].We = (const float*)d_in[base + 6];
        p[l].Ws = (const float*)d_in[base + 7]; p[l].bs = (const float*)d_in[base + 8];
    }
    const float* lng = (const float*)d_in[30];
    const float* lnb = (const float*)d_in[31];

    // Workspace: ~91 MB
    char* ws = (char*)d_ws;
    size_t off = 0;
    auto alloc = [&](size_t bytes) { void* pp = ws + off; off += (bytes + 255) & ~(size_t)255; return pp; };
    int*   rowptr = (int*)  alloc((NNODES + 1) * 4);
    int*   cursor = (int*)  alloc(NNODES * 4);
    int*   deg    = (int*)  alloc(NNODES * 4);
    int4*  csr4   = (int4*) alloc((size_t)NEDGES * 16);
    bf16*  hbuf   = (bf16*) alloc((size_t)NNODES * 64 * 2);
    bf16*  comb   = (bf16*) alloc((size_t)NNODES * CW * 2);   // 57.6 MB
    float* alphas = (float*)alloc((size_t)NEDGES * 4 * 4);    // 12.8 MB
    float* wqwe   = (float*)alloc((size_t)129 * 64 * 4);
    bf16*  Wc1    = (bf16*) alloc((size_t)CW * 128 * 2);
    bf16*  Wc2    = (bf16*) alloc((size_t)320 * 128 * 2);
    float* b1     = (float*)alloc(CW * 4);
    float* b2     = (float*)alloc(320 * 4);

    const int* srcArr = eidx;           // edge_index[0]
    const int* dstArr = eidx + NEDGES;  // edge_index[1]

    // CSR build
    hipMemsetAsync(deg, 0, NNODES * 4, stream);
    hist_kernel<<<(NEDGES + 255) / 256, 256, 0, stream>>>(dstArr, deg, NEDGES);
    scan_kernel<<<1, 1024, 0, stream>>>(deg, rowptr, cursor, NNODES);
    scatter_kernel<<<(NEDGES + 255) / 256, 256, 0, stream>>>(srcArr, dstArr, cursor, csr4, NEDGES);

    int gE = (4 * NEDGES + 255) / 256;
    int gm = (NNODES + 63) / 64;
    int fins[3] = {128, 64, 64};

    const void* hin = x;
    for (int l = 0; l < 3; l++) {
        int FIN = fins[l];
        wqwe_kernel<<<FIN + 1, 64, 0, stream>>>(p[l].Wq, p[l].bq, p[l].We, wqwe, FIN);
        pack1<<<CW, FIN, 0, stream>>>(p[l].Wq, p[l].bq, p[l].Wk, p[l].bk, wqwe, Wc1, b1, FIN);
        pack2<<<320, FIN, 0, stream>>>(p[l].Wv, p[l].bv, p[l].Ws, p[l].bs, Wc2, b2, FIN);
        // pass1: q|k|qwe
        if (l == 0) gemm_mfma<float><<<dim3(gm, 9), 256, 0, stream>>>((const float*)hin, FIN, Wc1, b1, NNODES, comb, CW);
        else        gemm_mfma<bf16> <<<dim3(gm, 9), 256, 0, stream>>>((const bf16*)hin,  FIN, Wc1, b1, NNODES, comb, CW);
        // edge scores in CSR order
        edge_logits<<<gE, 256, 0, stream>>>(csr4, eattr, (const u16*)comb, alphas, NEDGES);
        // pass2: v|skip (overwrites q/k region after edge_logits; stream-ordered)
        if (l == 0) gemm_mfma<float><<<dim3(gm, 5), 256, 0, stream>>>((const float*)hin, FIN, Wc2, b2, NNODES, comb, CW);
        else        gemm_mfma<bf16> <<<dim3(gm, 5), 256, 0, stream>>>((const bf16*)hin,  FIN, Wc2, b2, NNODES, comb, CW);
        // aggregate + LN + GELU
        node_agg<<<NNODES, 256, 0, stream>>>(rowptr, csr4, alphas, eattr, (const u16*)comb,
            p[l].We, lng, lnb, (l == 2) ? nullptr : hbuf, (l == 2) ? (float*)d_out : nullptr);
        hin = hbuf;
    }
}

// Round 9
// 1171.722 us; speedup vs baseline: 4.0318x; 1.2211x over previous
//
#include <hip/hip_runtime.h>
#include <hip/hip_bf16.h>
#include <math.h>

#define NNODES 50000
#define NEDGES 800000
#define HD     256   // HEADS*DHEAD
#define CW     576   // combined buffer width: q(256)|k(256)|qwe(64); pass2: v(256)|skip(64)

typedef __hip_bfloat16 bf16;
typedef unsigned short u16;
typedef unsigned int   u32;
typedef __attribute__((ext_vector_type(8))) short bf16x8;
typedef __attribute__((ext_vector_type(4))) float f32x4;

__device__ __forceinline__ float b2f(bf16 v) { return __bfloat162float(v); }
__device__ __forceinline__ float ldf(const float* p) { return *p; }
__device__ __forceinline__ float ldf(const bf16* p)  { return __bfloat162float(*p); }
__device__ __forceinline__ float lo16f(u32 u) { return __uint_as_float(u << 16); }
__device__ __forceinline__ float hi16f(u32 u) { return __uint_as_float(u & 0xFFFF0000u); }
__device__ __forceinline__ short f2s(float v) { __hip_bfloat16 h = __float2bfloat16(v); return *(short*)&h; }
__device__ __forceinline__ uint2 ldu2(const u16* p) { return *(const uint2*)p; }

// ---------------- CSR build ----------------
__global__ void hist_kernel(const int* __restrict__ dst, int* __restrict__ deg, int E) {
    int e = blockIdx.x * 256 + threadIdx.x;
    if (e < E) atomicAdd(&deg[dst[e]], 1);
}

// multi-block scan: A) per-256-block inclusive scan, B) scan block sums, C) combine
__global__ void scanA(const int* __restrict__ deg, int* __restrict__ locincl,
                      int* __restrict__ blocksum, int n) {
    int tid = threadIdx.x;
    int i = blockIdx.x * 256 + tid;
    int v = (i < n) ? deg[i] : 0;
    int lane = tid & 63, w = tid >> 6;
    int s = v;
    #pragma unroll
    for (int off = 1; off < 64; off <<= 1) {
        int t = __shfl_up(s, off);
        if (lane >= off) s += t;
    }
    __shared__ int wsum[4];
    if (lane == 63) wsum[w] = s;
    __syncthreads();
    for (int ww = 0; ww < w; ww++) s += wsum[ww];
    if (i < n) locincl[i] = s;
    if (tid == 255) blocksum[blockIdx.x] = s;
}

__global__ void scanB(const int* __restrict__ blocksum, int* __restrict__ blockoff,
                      int nb, int* __restrict__ rowptr, int n) {
    int tid = threadIdx.x;           // single block, 256 threads, nb <= 256
    int v = (tid < nb) ? blocksum[tid] : 0;
    int lane = tid & 63, w = tid >> 6;
    int s = v;
    #pragma unroll
    for (int off = 1; off < 64; off <<= 1) {
        int t = __shfl_up(s, off);
        if (lane >= off) s += t;
    }
    __shared__ int wsum[4];
    if (lane == 63) wsum[w] = s;
    __syncthreads();
    for (int ww = 0; ww < w; ww++) s += wsum[ww];
    if (tid < nb) blockoff[tid] = s - v;     // exclusive
    if (tid == 255) rowptr[n] = s;           // grand total
}

__global__ void scanC(const int* __restrict__ deg, const int* __restrict__ locincl,
                      const int* __restrict__ blockoff,
                      int* __restrict__ rowptr, int* __restrict__ cursor, int n) {
    int i = blockIdx.x * 256 + threadIdx.x;
    if (i < n) {
        int ex = locincl[i] - deg[i] + blockoff[blockIdx.x];
        rowptr[i] = ex;
        cursor[i] = ex;
    }
}

__global__ void scatter_kernel(const int* __restrict__ src, const int* __restrict__ dst,
                               int* __restrict__ cursor, int4* __restrict__ csr4, int E) {
    int e = blockIdx.x * 256 + threadIdx.x;
    if (e < E) {
        int d = dst[e];
        int p = atomicAdd(&cursor[d], 1);
        csr4[p] = make_int4(src[e], e, d, 0);
    }
}

// WqWe[c][h*16+j] = sum_d Wq[c, h*64+d] * We[j, h*64+d]; row c==FIN is the bq-derived bias.
__global__ void wqwe_kernel(const float* __restrict__ Wq, const float* __restrict__ bq,
                            const float* __restrict__ We, float* __restrict__ out, int FIN) {
    int c = blockIdx.x;
    int t = threadIdx.x;
    int h = t >> 4, j = t & 15;
    const float* qrow = (c == FIN) ? bq : (Wq + (size_t)c * HD);
    float s = 0.f;
    #pragma unroll 8
    for (int d = 0; d < 64; d++) s += qrow[h * 64 + d] * We[j * HD + h * 64 + d];
    out[c * 64 + t] = s;
}

// ---- weight packs: n-major bf16 [N][K] + fp32 bias ----
__global__ void pack1(const float* __restrict__ Wq, const float* __restrict__ bq,
                      const float* __restrict__ Wk, const float* __restrict__ bk,
                      const float* __restrict__ wqwe,
                      bf16* __restrict__ Wc, float* __restrict__ b, int K) {
    int n = blockIdx.x, c = threadIdx.x;
    float v;
    if (n < 256)      v = Wq[(size_t)c * 256 + n];
    else if (n < 512) v = Wk[(size_t)c * 256 + n - 256];
    else              v = wqwe[c * 64 + n - 512];
    Wc[(size_t)n * K + c] = __float2bfloat16(v);
    if (c == 0) b[n] = (n < 256) ? bq[n] : (n < 512 ? bk[n - 256] : wqwe[K * 64 + n - 512]);
}

__global__ void pack2(const float* __restrict__ Wv, const float* __restrict__ bv,
                      const float* __restrict__ Ws, const float* __restrict__ bs,
                      bf16* __restrict__ Wc, float* __restrict__ b, int K) {
    int n = blockIdx.x, c = threadIdx.x;
    float v = (n < 256) ? Wv[(size_t)c * 256 + n] : Ws[(size_t)c * 64 + n - 256];
    Wc[(size_t)n * K + c] = __float2bfloat16(v);
    if (c == 0) b[n] = (n < 256) ? bv[n] : bs[n - 256];
}

// ---------------- MFMA bf16 GEMM: out[M x ldo] = A[M x K] @ Wc^T + bias ----------------
template<typename TA>
__global__ void __launch_bounds__(256) gemm_mfma(
    const TA* __restrict__ A, int K,
    const bf16* __restrict__ Wc, const float* __restrict__ bias,
    int M, bf16* __restrict__ out, int ldo)
{
    __shared__ short Al[64 * 40];
    __shared__ short Bl[64 * 40];
    int m0 = blockIdx.x * 64, n0 = blockIdx.y * 64;
    int tid = threadIdx.x;
    int w = tid >> 6, lane = tid & 63;
    int lr = tid >> 2, lc = (tid & 3) * 8;
    f32x4 acc[4] = {};

    for (int k0 = 0; k0 < K; k0 += 32) {
        __syncthreads();
        {
            int m = m0 + lr;
            uint4 val = make_uint4(0, 0, 0, 0);
            if (m < M) {
                if constexpr (sizeof(TA) == 4) {
                    const float4* ap = (const float4*)((const float*)A + (size_t)m * K + k0 + lc);
                    float4 f0 = ap[0], f1 = ap[1];
                    union { short s[8]; uint4 u; } t;
                    t.s[0] = f2s(f0.x); t.s[1] = f2s(f0.y); t.s[2] = f2s(f0.z); t.s[3] = f2s(f0.w);
                    t.s[4] = f2s(f1.x); t.s[5] = f2s(f1.y); t.s[6] = f2s(f1.z); t.s[7] = f2s(f1.w);
                    val = t.u;
                } else {
                    val = *(const uint4*)((const u16*)A + (size_t)m * K + k0 + lc);
                }
            }
            *(uint4*)&Al[lr * 40 + lc] = val;
        }
        *(uint4*)&Bl[lr * 40 + lc] = *(const uint4*)((const u16*)Wc + (size_t)(n0 + lr) * K + k0 + lc);
        __syncthreads();

        int am = lane & 15, aq = lane >> 4;
        bf16x8 af = *(const bf16x8*)&Al[(w * 16 + am) * 40 + aq * 8];
        #pragma unroll
        for (int t = 0; t < 4; t++) {
            bf16x8 bfr = *(const bf16x8*)&Bl[(t * 16 + am) * 40 + aq * 8];
            acc[t] = __builtin_amdgcn_mfma_f32_16x16x32_bf16(af, bfr, acc[t], 0, 0, 0);
        }
    }
    int cl = lane & 15, rq = lane >> 4;
    #pragma unroll
    for (int t = 0; t < 4; t++) {
        int c = n0 + t * 16 + cl;
        float bv = bias[c];
        #pragma unroll
        for (int r = 0; r < 4; r++) {
            int m = m0 + w * 16 + rq * 4 + r;
            if (m < M) out[(size_t)m * ldo + c] = __float2bfloat16(acc[t][r] + bv);
        }
    }
}

// ---------------- edge scores in CSR (dst-major) order: thread = (csr_pos, head) ----------------
__global__ void __launch_bounds__(256) edge_logits(
    const int4* __restrict__ csr4, const float* __restrict__ eattr,
    const u16* __restrict__ comb, float* __restrict__ alphas, int E)
{
    int t = blockIdx.x * 256 + threadIdx.x;
    if (t >= 4 * E) return;
    int pos = t >> 2, h = t & 3;
    int4 c4 = csr4[pos];
    int sn = c4.x, eid = c4.y, dn = c4.z;
    const uint4* qp = (const uint4*)(comb + (size_t)dn * CW + (h << 6));
    const uint4* kp = (const uint4*)(comb + (size_t)sn * CW + 256 + (h << 6));
    float acc = 0.f;
    #pragma unroll
    for (int i = 0; i < 8; i++) {
        uint4 qa = qp[i], ka = kp[i];
        acc += lo16f(qa.x) * lo16f(ka.x) + hi16f(qa.x) * hi16f(ka.x)
             + lo16f(qa.y) * lo16f(ka.y) + hi16f(qa.y) * hi16f(ka.y)
             + lo16f(qa.z) * lo16f(ka.z) + hi16f(qa.z) * hi16f(ka.z)
             + lo16f(qa.w) * lo16f(ka.w) + hi16f(qa.w) * hi16f(ka.w);
    }
    const uint4*  wp = (const uint4*)(comb + (size_t)dn * CW + 512 + (h << 4));
    const float4* ep = (const float4*)(eattr + (size_t)eid * 16);
    #pragma unroll
    for (int i = 0; i < 2; i++) {
        uint4  wa = wp[i];
        float4 ea = ep[2 * i], eb = ep[2 * i + 1];
        acc += lo16f(wa.x) * ea.x + hi16f(wa.x) * ea.y + lo16f(wa.y) * ea.z + hi16f(wa.y) * ea.w
             + lo16f(wa.z) * eb.x + hi16f(wa.z) * eb.y + lo16f(wa.w) * eb.z + hi16f(wa.w) * eb.w;
    }
    alphas[t] = __expf(acc * 0.125f);    // SCALE=1/8; max-subtraction cancels exactly
}

// ---------------- node aggregation + epilogue (wave-per-edge, full 256-ch row) ----------------
// block = node; wave w handles edges i = w, w+4, ...; lane l covers channels 4l..4l+3
// (head = l>>4 for all four), so ONE alpha load per lane serves v and ea accumulation.
__global__ void __launch_bounds__(256) node_agg(
    const int* __restrict__ rowptr, const int4* __restrict__ csr4,
    const float* __restrict__ alphas, const float* __restrict__ eattr,
    const u16* __restrict__ comb, const float* __restrict__ We,
    const float* __restrict__ lng, const float* __restrict__ lnb,
    bf16* __restrict__ outB, float* __restrict__ outF)
{
    int n = blockIdx.x;
    int tid = threadIdx.x, w = tid >> 6, lane = tid & 63;
    int hg = lane >> 4, j16 = lane & 15;
    __shared__ int   sh_src[64], sh_eid[64];
    __shared__ float sAV[4][256];
    __shared__ float sAE[4][64];
    __shared__ float sSS[4][4];

    int e0 = rowptr[n], e1 = rowptr[n + 1];
    float av0 = 0.f, av1 = 0.f, av2 = 0.f, av3 = 0.f, ae = 0.f, ss = 0.f;
    int coff = 4 * lane;   // channel offset within the v row

    for (int base = e0; base < e1; base += 64) {
        int cnt = e1 - base; if (cnt > 64) cnt = 64;
        __syncthreads();
        if (tid < cnt) {
            int4 c4 = csr4[base + tid];
            sh_src[tid] = c4.x;
            sh_eid[tid] = c4.y;
        }
        __syncthreads();
        int i = w;
        for (; i + 12 < cnt; i += 16) {
            int s0 = sh_src[i], s1 = sh_src[i + 4], s2 = sh_src[i + 8], s3 = sh_src[i + 12];
            int q0 = sh_eid[i], q1 = sh_eid[i + 4], q2 = sh_eid[i + 8], q3 = sh_eid[i + 12];
            float a0 = alphas[(size_t)(base + i) * 4 + hg];
            float a1 = alphas[(size_t)(base + i + 4) * 4 + hg];
            float a2 = alphas[(size_t)(base + i + 8) * 4 + hg];
            float a3 = alphas[(size_t)(base + i + 12) * 4 + hg];
            uint2 u0 = ldu2(comb + (size_t)s0 * CW + coff);
            uint2 u1 = ldu2(comb + (size_t)s1 * CW + coff);
            uint2 u2 = ldu2(comb + (size_t)s2 * CW + coff);
            uint2 u3 = ldu2(comb + (size_t)s3 * CW + coff);
            float e0v = eattr[(size_t)q0 * 16 + j16];
            float e1v = eattr[(size_t)q1 * 16 + j16];
            float e2v = eattr[(size_t)q2 * 16 + j16];
            float e3v = eattr[(size_t)q3 * 16 + j16];
            ss += a0; av0 += a0 * lo16f(u0.x); av1 += a0 * hi16f(u0.x);
                      av2 += a0 * lo16f(u0.y); av3 += a0 * hi16f(u0.y); ae += a0 * e0v;
            ss += a1; av0 += a1 * lo16f(u1.x); av1 += a1 * hi16f(u1.x);
                      av2 += a1 * lo16f(u1.y); av3 += a1 * hi16f(u1.y); ae += a1 * e1v;
            ss += a2; av0 += a2 * lo16f(u2.x); av1 += a2 * hi16f(u2.x);
                      av2 += a2 * lo16f(u2.y); av3 += a2 * hi16f(u2.y); ae += a2 * e2v;
            ss += a3; av0 += a3 * lo16f(u3.x); av1 += a3 * hi16f(u3.x);
                      av2 += a3 * lo16f(u3.y); av3 += a3 * hi16f(u3.y); ae += a3 * e3v;
        }
        for (; i < cnt; i += 4) {
            int s0 = sh_src[i], q0 = sh_eid[i];
            float a0 = alphas[(size_t)(base + i) * 4 + hg];
            uint2 u0 = ldu2(comb + (size_t)s0 * CW + coff);
            float e0v = eattr[(size_t)q0 * 16 + j16];
            ss += a0; av0 += a0 * lo16f(u0.x); av1 += a0 * hi16f(u0.x);
                      av2 += a0 * lo16f(u0.y); av3 += a0 * hi16f(u0.y); ae += a0 * e0v;
        }
    }

    *(float4*)&sAV[w][coff] = make_float4(av0, av1, av2, av3);
    sAE[w][lane] = ae;
    if (j16 == 0) sSS[w][hg] = ss;
    __syncthreads();

    if (w == 0) {
        float inv[4];
        #pragma unroll
        for (int h = 0; h < 4; h++) {
            float S = sSS[0][h] + sSS[1][h] + sSS[2][h] + sSS[3][h];
            inv[h] = (S > 0.f) ? 1.f / S : 0.f;
        }
        // lane-parallel AE total, pre-scaled by inv[head]
        {
            float aet = sAE[0][lane] + sAE[1][lane] + sAE[2][lane] + sAE[3][lane];
            sAE[0][lane] = aet * inv[hg];
        }
        int d = lane;
        float val = 0.f;
        #pragma unroll
        for (int h = 0; h < 4; h++) {
            int c = h * 64 + d;
            float AV = sAV[0][c] + sAV[1][c] + sAV[2][c] + sAV[3][c];
            float xv = AV * inv[h];
            #pragma unroll
            for (int j = 0; j < 16; j++) xv += sAE[0][h * 16 + j] * We[j * HD + c];
            val += xv;
        }
        val = val * 0.25f + __uint_as_float((u32)comb[(size_t)n * CW + 256 + d] << 16);
        float m = val;
        #pragma unroll
        for (int off = 1; off < 64; off <<= 1) m += __shfl_xor(m, off);
        m *= (1.f / 64.f);
        float diff = val - m;
        float vr = diff * diff;
        #pragma unroll
        for (int off = 1; off < 64; off <<= 1) vr += __shfl_xor(vr, off);
        vr *= (1.f / 64.f);
        float y = diff * rsqrtf(vr + 1e-5f) * lng[d] + lnb[d];
        float ge = 0.5f * y * (1.f + erff(y * 0.70710678118654752f));   // exact GELU
        if (outF) outF[(size_t)n * 64 + d] = ge;
        else      outB[(size_t)n * 64 + d] = __float2bfloat16(ge);
    }
}

extern "C" void kernel_launch(void* const* d_in, const int* in_sizes, int n_in,
                              void* d_out, int out_size, void* d_ws, size_t ws_size,
                              hipStream_t stream)
{
    const float* x     = (const float*)d_in[0];
    const int*   eidx  = (const int*)d_in[1];
    const float* eattr = (const float*)d_in[2];
    struct P { const float *Wq,*bq,*Wk,*bk,*Wv,*bv,*We,*Ws,*bs; };
    P p[3];
    for (int l = 0; l < 3; l++) {
        int base = 3 + l * 9;
        p[l].Wq = (const float*)d_in[base + 0]; p[l].bq = (const float*)d_in[base + 1];
        p[l].Wk = (const float*)d_in[base + 2]; p[l].bk = (const float*)d_in[base + 3];
        p[l].Wv = (const float*)d_in[base + 4]; p[l].bv = (const float*)d_in[base + 5];
        p[l].We = (const float*)d_in[base + 6];
        p[l].Ws = (const float*)d_in[base + 7]; p[l].bs = (const float*)d_in[base + 8];
    }
    const float* lng = (const float*)d_in[30];
    const float* lnb = (const float*)d_in[31];

    // Workspace: ~91 MB
    char* ws = (char*)d_ws;
    size_t off = 0;
    auto alloc = [&](size_t bytes) { void* pp = ws + off; off += (bytes + 255) & ~(size_t)255; return pp; };
    int*   rowptr   = (int*)  alloc((NNODES + 1) * 4);
    int*   cursor   = (int*)  alloc(NNODES * 4);
    int*   deg      = (int*)  alloc(NNODES * 4);
    int*   blocksum = (int*)  alloc(256 * 4);
    int*   blockoff = (int*)  alloc(256 * 4);
    int4*  csr4     = (int4*) alloc((size_t)NEDGES * 16);
    bf16*  hbuf     = (bf16*) alloc((size_t)NNODES * 64 * 2);
    bf16*  comb     = (bf16*) alloc((size_t)NNODES * CW * 2);   // 57.6 MB
    float* alphas   = (float*)alloc((size_t)NEDGES * 4 * 4);    // 12.8 MB
    float* wqwe     = (float*)alloc((size_t)129 * 64 * 4);
    bf16*  Wc1      = (bf16*) alloc((size_t)CW * 128 * 2);
    bf16*  Wc2      = (bf16*) alloc((size_t)320 * 128 * 2);
    float* b1       = (float*)alloc(CW * 4);
    float* b2       = (float*)alloc(320 * 4);

    const int* srcArr = eidx;           // edge_index[0]
    const int* dstArr = eidx + NEDGES;  // edge_index[1]

    // CSR build (multi-block scan)
    int NB = (NNODES + 255) / 256;
    hipMemsetAsync(deg, 0, NNODES * 4, stream);
    hist_kernel<<<(NEDGES + 255) / 256, 256, 0, stream>>>(dstArr, deg, NEDGES);
    scanA<<<NB, 256, 0, stream>>>(deg, cursor, blocksum, NNODES);          // cursor <- local inclusive
    scanB<<<1, 256, 0, stream>>>(blocksum, blockoff, NB, rowptr, NNODES);  // rowptr[N] <- total
    scanC<<<NB, 256, 0, stream>>>(deg, cursor, blockoff, rowptr, cursor, NNODES);
    scatter_kernel<<<(NEDGES + 255) / 256, 256, 0, stream>>>(srcArr, dstArr, cursor, csr4, NEDGES);

    int gE = (4 * NEDGES + 255) / 256;
    int gm = (NNODES + 63) / 64;
    int fins[3] = {128, 64, 64};

    const void* hin = x;
    for (int l = 0; l < 3; l++) {
        int FIN = fins[l];
        wqwe_kernel<<<FIN + 1, 64, 0, stream>>>(p[l].Wq, p[l].bq, p[l].We, wqwe, FIN);
        pack1<<<CW, FIN, 0, stream>>>(p[l].Wq, p[l].bq, p[l].Wk, p[l].bk, wqwe, Wc1, b1, FIN);
        pack2<<<320, FIN, 0, stream>>>(p[l].Wv, p[l].bv, p[l].Ws, p[l].bs, Wc2, b2, FIN);
        // pass1: q|k|qwe
        if (l == 0) gemm_mfma<float><<<dim3(gm, 9), 256, 0, stream>>>((const float*)hin, FIN, Wc1, b1, NNODES, comb, CW);
        else        gemm_mfma<bf16> <<<dim3(gm, 9), 256, 0, stream>>>((const bf16*)hin,  FIN, Wc1, b1, NNODES, comb, CW);
        // edge scores in CSR order
        edge_logits<<<gE, 256, 0, stream>>>(csr4, eattr, (const u16*)comb, alphas, NEDGES);
        // pass2: v|skip (overwrites q/k region after edge_logits; stream-ordered)
        if (l == 0) gemm_mfma<float><<<dim3(gm, 5), 256, 0, stream>>>((const float*)hin, FIN, Wc2, b2, NNODES, comb, CW);
        else        gemm_mfma<bf16> <<<dim3(gm, 5), 256, 0, stream>>>((const bf16*)hin,  FIN, Wc2, b2, NNODES, comb, CW);
        // aggregate + LN + GELU
        node_agg<<<NNODES, 256, 0, stream>>>(rowptr, csr4, alphas, eattr, (const u16*)comb,
            p[l].We, lng, lnb, (l == 2) ? nullptr : hbuf, (l == 2) ? (float*)d_out : nullptr);
        hin = hbuf;
    }
}

// Round 11
// 1019.483 us; speedup vs baseline: 4.6338x; 1.1493x over previous
//
#include <hip/hip_runtime.h>
#include <hip/hip_bf16.h>
#include <math.h>

#define NNODES 50000
#define NEDGES 800000
#define HD     256   // HEADS*DHEAD
#define CW     320   // comb width: pass1 q(256)|qwe(64); pass2 v(256)|skip(64)

typedef __hip_bfloat16 bf16;
typedef unsigned short u16;
typedef unsigned char  u8;
typedef unsigned int   u32;
typedef __attribute__((ext_vector_type(8))) short bf16x8;
typedef __attribute__((ext_vector_type(4))) float f32x4;
typedef __attribute__((ext_vector_type(2))) float f32x2;

__device__ __forceinline__ float b2f(bf16 v) { return __bfloat162float(v); }
__device__ __forceinline__ float ldf(const float* p) { return *p; }
__device__ __forceinline__ float ldf(const bf16* p)  { return __bfloat162float(*p); }
__device__ __forceinline__ float lo16f(u32 u) { return __uint_as_float(u << 16); }
__device__ __forceinline__ float hi16f(u32 u) { return __uint_as_float(u & 0xFFFF0000u); }
__device__ __forceinline__ short f2s(float v) { __hip_bfloat16 h = __float2bfloat16(v); return *(short*)&h; }
__device__ __forceinline__ uint2 ldu2(const u16* p) { return *(const uint2*)p; }

// ---------------- CSR build ----------------
__global__ void hist_kernel(const int* __restrict__ dst, int* __restrict__ deg, int E) {
    int e = blockIdx.x * 256 + threadIdx.x;
    if (e < E) atomicAdd(&deg[dst[e]], 1);
}

__global__ void scanA(const int* __restrict__ deg, int* __restrict__ locincl,
                      int* __restrict__ blocksum, int n) {
    int tid = threadIdx.x;
    int i = blockIdx.x * 256 + tid;
    int v = (i < n) ? deg[i] : 0;
    int lane = tid & 63, w = tid >> 6;
    int s = v;
    #pragma unroll
    for (int off = 1; off < 64; off <<= 1) {
        int t = __shfl_up(s, off);
        if (lane >= off) s += t;
    }
    __shared__ int wsum[4];
    if (lane == 63) wsum[w] = s;
    __syncthreads();
    for (int ww = 0; ww < w; ww++) s += wsum[ww];
    if (i < n) locincl[i] = s;
    if (tid == 255) blocksum[blockIdx.x] = s;
}

__global__ void scanB(const int* __restrict__ blocksum, int* __restrict__ blockoff,
                      int nb, int* __restrict__ rowptr, int n) {
    int tid = threadIdx.x;
    int v = (tid < nb) ? blocksum[tid] : 0;
    int lane = tid & 63, w = tid >> 6;
    int s = v;
    #pragma unroll
    for (int off = 1; off < 64; off <<= 1) {
        int t = __shfl_up(s, off);
        if (lane >= off) s += t;
    }
    __shared__ int wsum[4];
    if (lane == 63) wsum[w] = s;
    __syncthreads();
    for (int ww = 0; ww < w; ww++) s += wsum[ww];
    if (tid < nb) blockoff[tid] = s - v;
    if (tid == 255) rowptr[n] = s;
}

__global__ void scanC(const int* __restrict__ deg, const int* __restrict__ locincl,
                      const int* __restrict__ blockoff,
                      int* __restrict__ rowptr, int* __restrict__ cursor, int n) {
    int i = blockIdx.x * 256 + threadIdx.x;
    if (i < n) {
        int ex = locincl[i] - deg[i] + blockoff[blockIdx.x];
        rowptr[i] = ex;
        cursor[i] = ex;
    }
}

__global__ void scatter_kernel(const int* __restrict__ src, const int* __restrict__ dst,
                               int* __restrict__ cursor, int4* __restrict__ csr4, int E) {
    int e = blockIdx.x * 256 + threadIdx.x;
    if (e < E) {
        int d = dst[e];
        int p = atomicAdd(&cursor[d], 1);
        csr4[p] = make_int4(src[e], e, d, 0);
    }
}

// WqWe[c][h*16+j] = sum_d Wq[c, h*64+d] * We[j, h*64+d]; row c==FIN is the bq-derived bias.
__global__ void wqwe_kernel(const float* __restrict__ Wq, const float* __restrict__ bq,
                            const float* __restrict__ We, float* __restrict__ out, int FIN) {
    int c = blockIdx.x;
    int t = threadIdx.x;
    int h = t >> 4, j = t & 15;
    const float* qrow = (c == FIN) ? bq : (Wq + (size_t)c * HD);
    float s = 0.f;
    #pragma unroll 8
    for (int d = 0; d < 64; d++) s += qrow[h * 64 + d] * We[j * HD + h * 64 + d];
    out[c * 64 + t] = s;
}

// ---- weight packs: n-major bf16 [N][K] + fp32 bias ----
__global__ void pack1(const float* __restrict__ Wq, const float* __restrict__ bq,
                      const float* __restrict__ wqwe,
                      bf16* __restrict__ Wc, float* __restrict__ b, int K) {
    int n = blockIdx.x, c = threadIdx.x;   // 320 rows: q | qwe
    float v = (n < 256) ? Wq[(size_t)c * 256 + n] : wqwe[c * 64 + n - 256];
    Wc[(size_t)n * K + c] = __float2bfloat16(v);
    if (c == 0) b[n] = (n < 256) ? bq[n] : wqwe[K * 64 + n - 256];
}

__global__ void packK(const float* __restrict__ Wk, const float* __restrict__ bk,
                      bf16* __restrict__ Wc, float* __restrict__ b, int K) {
    int n = blockIdx.x, c = threadIdx.x;   // 256 rows: k
    Wc[(size_t)n * K + c] = __float2bfloat16(Wk[(size_t)c * 256 + n]);
    if (c == 0) b[n] = bk[n];
}

__global__ void pack2(const float* __restrict__ Wv, const float* __restrict__ bv,
                      const float* __restrict__ Ws, const float* __restrict__ bs,
                      bf16* __restrict__ Wc, float* __restrict__ b, int K) {
    int n = blockIdx.x, c = threadIdx.x;   // 320 rows: v | skip
    float v = (n < 256) ? Wv[(size_t)c * 256 + n] : Ws[(size_t)c * 64 + n - 256];
    Wc[(size_t)n * K + c] = __float2bfloat16(v);
    if (c == 0) b[n] = (n < 256) ? bv[n] : bs[n - 256];
}

// ---------------- MFMA bf16 GEMM: out[M x ldo] = A[M x K] @ Wc^T + bias ----------------
// OUT8: write fp8-e4m3 bytes (for the k buffer) instead of bf16.
template<typename TA, bool OUT8>
__global__ void __launch_bounds__(256) gemm_mfma(
    const TA* __restrict__ A, int K,
    const bf16* __restrict__ Wc, const float* __restrict__ bias,
    int M, void* __restrict__ outp, int ldo)
{
    __shared__ short Al[64 * 40];
    __shared__ short Bl[64 * 40];
    int m0 = blockIdx.x * 64, n0 = blockIdx.y * 64;
    int tid = threadIdx.x;
    int w = tid >> 6, lane = tid & 63;
    int lr = tid >> 2, lc = (tid & 3) * 8;
    f32x4 acc[4] = {};

    for (int k0 = 0; k0 < K; k0 += 32) {
        __syncthreads();
        {
            int m = m0 + lr;
            uint4 val = make_uint4(0, 0, 0, 0);
            if (m < M) {
                if constexpr (sizeof(TA) == 4) {
                    const float4* ap = (const float4*)((const float*)A + (size_t)m * K + k0 + lc);
                    float4 f0 = ap[0], f1 = ap[1];
                    union { short s[8]; uint4 u; } t;
                    t.s[0] = f2s(f0.x); t.s[1] = f2s(f0.y); t.s[2] = f2s(f0.z); t.s[3] = f2s(f0.w);
                    t.s[4] = f2s(f1.x); t.s[5] = f2s(f1.y); t.s[6] = f2s(f1.z); t.s[7] = f2s(f1.w);
                    val = t.u;
                } else {
                    val = *(const uint4*)((const u16*)A + (size_t)m * K + k0 + lc);
                }
            }
            *(uint4*)&Al[lr * 40 + lc] = val;
        }
        *(uint4*)&Bl[lr * 40 + lc] = *(const uint4*)((const u16*)Wc + (size_t)(n0 + lr) * K + k0 + lc);
        __syncthreads();

        int am = lane & 15, aq = lane >> 4;
        bf16x8 af = *(const bf16x8*)&Al[(w * 16 + am) * 40 + aq * 8];
        #pragma unroll
        for (int t = 0; t < 4; t++) {
            bf16x8 bfr = *(const bf16x8*)&Bl[(t * 16 + am) * 40 + aq * 8];
            acc[t] = __builtin_amdgcn_mfma_f32_16x16x32_bf16(af, bfr, acc[t], 0, 0, 0);
        }
    }
    int cl = lane & 15, rq = lane >> 4;
    #pragma unroll
    for (int t = 0; t < 4; t++) {
        int c = n0 + t * 16 + cl;
        float bv = bias[c];
        #pragma unroll
        for (int r = 0; r < 4; r++) {
            int m = m0 + w * 16 + rq * 4 + r;
            if (m < M) {
                float v = acc[t][r] + bv;
                if constexpr (OUT8) {
                    int pk = __builtin_amdgcn_cvt_pk_fp8_f32(v, v, 0, false);
                    ((u8*)outp)[(size_t)m * ldo + c] = (u8)(pk & 0xFF);
                } else {
                    ((bf16*)outp)[(size_t)m * ldo + c] = __float2bfloat16(v);
                }
            }
        }
    }
}

// ---------------- edge scores in CSR (dst-major) order: thread = (csr_pos, head) ----------------
// q/qwe from comb (bf16, dst-major -> cached); k from k8 (fp8 e4m3, random gather, half bytes).
__global__ void __launch_bounds__(256) edge_logits(
    const int4* __restrict__ csr4, const float* __restrict__ eattr,
    const u16* __restrict__ comb, const u8* __restrict__ k8,
    float* __restrict__ alphas, int E)
{
    int t = blockIdx.x * 256 + threadIdx.x;
    if (t >= 4 * E) return;
    int pos = t >> 2, h = t & 3;
    int4 c4 = csr4[pos];
    int sn = c4.x, eid = c4.y, dn = c4.z;
    const uint4* qp = (const uint4*)(comb + (size_t)dn * CW + (h << 6));
    const uint4* kp = (const uint4*)(k8 + (size_t)sn * 256 + (h << 6));
    float acc = 0.f;
    #pragma unroll
    for (int i = 0; i < 4; i++) {
        uint4 kw = kp[i];                    // 16 fp8 channels
        uint4 qa = qp[2 * i], qb = qp[2 * i + 1];
        f32x2 p0 = __builtin_amdgcn_cvt_pk_f32_fp8(kw.x, false);
        f32x2 p1 = __builtin_amdgcn_cvt_pk_f32_fp8(kw.x, true);
        f32x2 p2 = __builtin_amdgcn_cvt_pk_f32_fp8(kw.y, false);
        f32x2 p3 = __builtin_amdgcn_cvt_pk_f32_fp8(kw.y, true);
        f32x2 p4 = __builtin_amdgcn_cvt_pk_f32_fp8(kw.z, false);
        f32x2 p5 = __builtin_amdgcn_cvt_pk_f32_fp8(kw.z, true);
        f32x2 p6 = __builtin_amdgcn_cvt_pk_f32_fp8(kw.w, false);
        f32x2 p7 = __builtin_amdgcn_cvt_pk_f32_fp8(kw.w, true);
        acc += lo16f(qa.x) * p0[0] + hi16f(qa.x) * p0[1]
             + lo16f(qa.y) * p1[0] + hi16f(qa.y) * p1[1]
             + lo16f(qa.z) * p2[0] + hi16f(qa.z) * p2[1]
             + lo16f(qa.w) * p3[0] + hi16f(qa.w) * p3[1]
             + lo16f(qb.x) * p4[0] + hi16f(qb.x) * p4[1]
             + lo16f(qb.y) * p5[0] + hi16f(qb.y) * p5[1]
             + lo16f(qb.z) * p6[0] + hi16f(qb.z) * p6[1]
             + lo16f(qb.w) * p7[0] + hi16f(qb.w) * p7[1];
    }
    const uint4*  wp = (const uint4*)(comb + (size_t)dn * CW + 256 + (h << 4));
    const float4* ep = (const float4*)(eattr + (size_t)eid * 16);
    #pragma unroll
    for (int i = 0; i < 2; i++) {
        uint4  wa = wp[i];
        float4 ea = ep[2 * i], eb = ep[2 * i + 1];
        acc += lo16f(wa.x) * ea.x + hi16f(wa.x) * ea.y + lo16f(wa.y) * ea.z + hi16f(wa.y) * ea.w
             + lo16f(wa.z) * eb.x + hi16f(wa.z) * eb.y + lo16f(wa.w) * eb.z + hi16f(wa.w) * eb.w;
    }
    alphas[t] = __expf(acc * 0.125f);    // SCALE=1/8; max-subtraction cancels exactly
}

// ---------------- node aggregation + epilogue (wave-per-edge, full 256-ch row) ----------------
__global__ void __launch_bounds__(256) node_agg(
    const int* __restrict__ rowptr, const int4* __restrict__ csr4,
    const float* __restrict__ alphas, const float* __restrict__ eattr,
    const u16* __restrict__ comb, const float* __restrict__ We,
    const float* __restrict__ lng, const float* __restrict__ lnb,
    bf16* __restrict__ outB, float* __restrict__ outF)
{
    int n = blockIdx.x;
    int tid = threadIdx.x, w = tid >> 6, lane = tid & 63;
    int hg = lane >> 4, j16 = lane & 15;
    __shared__ int   sh_src[64], sh_eid[64];
    __shared__ float sAV[4][256];
    __shared__ float sAE[4][64];
    __shared__ float sSS[4][4];

    int e0 = rowptr[n], e1 = rowptr[n + 1];
    float av0 = 0.f, av1 = 0.f, av2 = 0.f, av3 = 0.f, ae = 0.f, ss = 0.f;
    int coff = 4 * lane;

    for (int base = e0; base < e1; base += 64) {
        int cnt = e1 - base; if (cnt > 64) cnt = 64;
        __syncthreads();
        if (tid < cnt) {
            int4 c4 = csr4[base + tid];
            sh_src[tid] = c4.x;
            sh_eid[tid] = c4.y;
        }
        __syncthreads();
        int i = w;
        for (; i + 12 < cnt; i += 16) {
            int s0 = sh_src[i], s1 = sh_src[i + 4], s2 = sh_src[i + 8], s3 = sh_src[i + 12];
            int q0 = sh_eid[i], q1 = sh_eid[i + 4], q2 = sh_eid[i + 8], q3 = sh_eid[i + 12];
            float a0 = alphas[(size_t)(base + i) * 4 + hg];
            float a1 = alphas[(size_t)(base + i + 4) * 4 + hg];
            float a2 = alphas[(size_t)(base + i + 8) * 4 + hg];
            float a3 = alphas[(size_t)(base + i + 12) * 4 + hg];
            uint2 u0 = ldu2(comb + (size_t)s0 * CW + coff);
            uint2 u1 = ldu2(comb + (size_t)s1 * CW + coff);
            uint2 u2 = ldu2(comb + (size_t)s2 * CW + coff);
            uint2 u3 = ldu2(comb + (size_t)s3 * CW + coff);
            float e0v = eattr[(size_t)q0 * 16 + j16];
            float e1v = eattr[(size_t)q1 * 16 + j16];
            float e2v = eattr[(size_t)q2 * 16 + j16];
            float e3v = eattr[(size_t)q3 * 16 + j16];
            ss += a0; av0 += a0 * lo16f(u0.x); av1 += a0 * hi16f(u0.x);
                      av2 += a0 * lo16f(u0.y); av3 += a0 * hi16f(u0.y); ae += a0 * e0v;
            ss += a1; av0 += a1 * lo16f(u1.x); av1 += a1 * hi16f(u1.x);
                      av2 += a1 * lo16f(u1.y); av3 += a1 * hi16f(u1.y); ae += a1 * e1v;
            ss += a2; av0 += a2 * lo16f(u2.x); av1 += a2 * hi16f(u2.x);
                      av2 += a2 * lo16f(u2.y); av3 += a2 * hi16f(u2.y); ae += a2 * e2v;
            ss += a3; av0 += a3 * lo16f(u3.x); av1 += a3 * hi16f(u3.x);
                      av2 += a3 * lo16f(u3.y); av3 += a3 * hi16f(u3.y); ae += a3 * e3v;
        }
        for (; i < cnt; i += 4) {
            int s0 = sh_src[i], q0 = sh_eid[i];
            float a0 = alphas[(size_t)(base + i) * 4 + hg];
            uint2 u0 = ldu2(comb + (size_t)s0 * CW + coff);
            float e0v = eattr[(size_t)q0 * 16 + j16];
            ss += a0; av0 += a0 * lo16f(u0.x); av1 += a0 * hi16f(u0.x);
                      av2 += a0 * lo16f(u0.y); av3 += a0 * hi16f(u0.y); ae += a0 * e0v;
        }
    }

    *(float4*)&sAV[w][coff] = make_float4(av0, av1, av2, av3);
    sAE[w][lane] = ae;
    if (j16 == 0) sSS[w][hg] = ss;
    __syncthreads();

    if (w == 0) {
        float inv[4];
        #pragma unroll
        for (int h = 0; h < 4; h++) {
            float S = sSS[0][h] + sSS[1][h] + sSS[2][h] + sSS[3][h];
            inv[h] = (S > 0.f) ? 1.f / S : 0.f;
        }
        {
            float aet = sAE[0][lane] + sAE[1][lane] + sAE[2][lane] + sAE[3][lane];
            sAE[0][lane] = aet * inv[hg];
        }
        int d = lane;
        float val = 0.f;
        #pragma unroll
        for (int h = 0; h < 4; h++) {
            int c = h * 64 + d;
            float AV = sAV[0][c] + sAV[1][c] + sAV[2][c] + sAV[3][c];
            float xv = AV * inv[h];
            #pragma unroll
            for (int j = 0; j < 16; j++) xv += sAE[0][h * 16 + j] * We[j * HD + c];
            val += xv;
        }
        val = val * 0.25f + __uint_as_float((u32)comb[(size_t)n * CW + 256 + d] << 16);
        float m = val;
        #pragma unroll
        for (int off = 1; off < 64; off <<= 1) m += __shfl_xor(m, off);
        m *= (1.f / 64.f);
        float diff = val - m;
        float vr = diff * diff;
        #pragma unroll
        for (int off = 1; off < 64; off <<= 1) vr += __shfl_xor(vr, off);
        vr *= (1.f / 64.f);
        float y = diff * rsqrtf(vr + 1e-5f) * lng[d] + lnb[d];
        float ge = 0.5f * y * (1.f + erff(y * 0.70710678118654752f));   // exact GELU
        if (outF) outF[(size_t)n * 64 + d] = ge;
        else      outB[(size_t)n * 64 + d] = __float2bfloat16(ge);
    }
}

extern "C" void kernel_launch(void* const* d_in, const int* in_sizes, int n_in,
                              void* d_out, int out_size, void* d_ws, size_t ws_size,
                              hipStream_t stream)
{
    const float* x     = (const float*)d_in[0];
    const int*   eidx  = (const int*)d_in[1];
    const float* eattr = (const float*)d_in[2];
    struct P { const float *Wq,*bq,*Wk,*bk,*Wv,*bv,*We,*Ws,*bs; };
    P p[3];
    for (int l = 0; l < 3; l++) {
        int base = 3 + l * 9;
        p[l].Wq = (const float*)d_in[base + 0]; p[l].bq = (const float*)d_in[base + 1];
        p[l].Wk = (const float*)d_in[base + 2]; p[l].bk = (const float*)d_in[base + 3];
        p[l].Wv = (const float*)d_in[base + 4]; p[l].bv = (const float*)d_in[base + 5];
        p[l].We = (const float*)d_in[base + 6];
        p[l].Ws = (const float*)d_in[base + 7]; p[l].bs = (const float*)d_in[base + 8];
    }
    const float* lng = (const float*)d_in[30];
    const float* lnb = (const float*)d_in[31];

    // Workspace: ~78 MB
    char* ws = (char*)d_ws;
    size_t off = 0;
    auto alloc = [&](size_t bytes) { void* pp = ws + off; off += (bytes + 255) & ~(size_t)255; return pp; };
    int*   rowptr   = (int*)  alloc((NNODES + 1) * 4);
    int*   cursor   = (int*)  alloc(NNODES * 4);
    int*   deg      = (int*)  alloc(NNODES * 4);
    int*   blocksum = (int*)  alloc(256 * 4);
    int*   blockoff = (int*)  alloc(256 * 4);
    int4*  csr4     = (int4*) alloc((size_t)NEDGES * 16);
    bf16*  hbuf     = (bf16*) alloc((size_t)NNODES * 64 * 2);
    bf16*  comb     = (bf16*) alloc((size_t)NNODES * CW * 2);   // 32 MB
    u8*    k8       = (u8*)   alloc((size_t)NNODES * 256);      // 12.8 MB fp8 k
    float* alphas   = (float*)alloc((size_t)NEDGES * 4 * 4);    // 12.8 MB
    float* wqwe     = (float*)alloc((size_t)129 * 64 * 4);
    bf16*  Wc1      = (bf16*) alloc((size_t)320 * 128 * 2);
    bf16*  WcK      = (bf16*) alloc((size_t)256 * 128 * 2);
    bf16*  Wc2      = (bf16*) alloc((size_t)320 * 128 * 2);
    float* b1       = (float*)alloc(320 * 4);
    float* bK       = (float*)alloc(256 * 4);
    float* b2       = (float*)alloc(320 * 4);

    const int* srcArr = eidx;           // edge_index[0]
    const int* dstArr = eidx + NEDGES;  // edge_index[1]

    // CSR build (multi-block scan)
    int NB = (NNODES + 255) / 256;
    (void)hipMemsetAsync(deg, 0, NNODES * 4, stream);
    hist_kernel<<<(NEDGES + 255) / 256, 256, 0, stream>>>(dstArr, deg, NEDGES);
    scanA<<<NB, 256, 0, stream>>>(deg, cursor, blocksum, NNODES);
    scanB<<<1, 256, 0, stream>>>(blocksum, blockoff, NB, rowptr, NNODES);
    scanC<<<NB, 256, 0, stream>>>(deg, cursor, blockoff, rowptr, cursor, NNODES);
    scatter_kernel<<<(NEDGES + 255) / 256, 256, 0, stream>>>(srcArr, dstArr, cursor, csr4, NEDGES);

    int gE = (4 * NEDGES + 255) / 256;
    int gm = (NNODES + 63) / 64;
    int fins[3] = {128, 64, 64};

    const void* hin = x;
    for (int l = 0; l < 3; l++) {
        int FIN = fins[l];
        wqwe_kernel<<<FIN + 1, 64, 0, stream>>>(p[l].Wq, p[l].bq, p[l].We, wqwe, FIN);
        pack1<<<320, FIN, 0, stream>>>(p[l].Wq, p[l].bq, wqwe, Wc1, b1, FIN);
        packK<<<256, FIN, 0, stream>>>(p[l].Wk, p[l].bk, WcK, bK, FIN);
        pack2<<<320, FIN, 0, stream>>>(p[l].Wv, p[l].bv, p[l].Ws, p[l].bs, Wc2, b2, FIN);
        // pass1: q|qwe (bf16) ; passK: k (fp8)
        if (l == 0) {
            gemm_mfma<float, false><<<dim3(gm, 5), 256, 0, stream>>>((const float*)hin, FIN, Wc1, b1, NNODES, comb, CW);
            gemm_mfma<float, true> <<<dim3(gm, 4), 256, 0, stream>>>((const float*)hin, FIN, WcK, bK, NNODES, k8, 256);
        } else {
            gemm_mfma<bf16, false><<<dim3(gm, 5), 256, 0, stream>>>((const bf16*)hin, FIN, Wc1, b1, NNODES, comb, CW);
            gemm_mfma<bf16, true> <<<dim3(gm, 4), 256, 0, stream>>>((const bf16*)hin, FIN, WcK, bK, NNODES, k8, 256);
        }
        // edge scores in CSR order
        edge_logits<<<gE, 256, 0, stream>>>(csr4, eattr, (const u16*)comb, k8, alphas, NEDGES);
        // pass2: v|skip (overwrites q|qwe region after edge_logits; stream-ordered)
        if (l == 0) gemm_mfma<float, false><<<dim3(gm, 5), 256, 0, stream>>>((const float*)hin, FIN, Wc2, b2, NNODES, comb, CW);
        else        gemm_mfma<bf16, false><<<dim3(gm, 5), 256, 0, stream>>>((const bf16*)hin,  FIN, Wc2, b2, NNODES, comb, CW);
        // aggregate + LN + GELU
        node_agg<<<NNODES, 256, 0, stream>>>(rowptr, csr4, alphas, eattr, (const u16*)comb,
            p[l].We, lng, lnb, (l == 2) ? nullptr : hbuf, (l == 2) ? (float*)d_out : nullptr);
        hin = hbuf;
    }
}